// Round 4
// baseline (232.326 us; speedup 1.0000x reference)
//
#include <hip/hip_runtime.h>
#include <math.h>

// Problem constants (reference file)
#define NPTS   500000
#define CIN    16
#define COUT   64
#define GRID_W 256
#define NCELL  65536

// ws layout (bytes)
#define WS_HIST   0                      // 65536 u32  (256 KB)
#define WS_STARTS 524288                 // 65536 u32 segment starts (256 KB)
#define WS_CR     786432                 // 500000 u32 (cell | lrank<<16) (2 MB)
#define WS_WPK    2883456                // 18432 f16 frag-packed weights (36864 B)
#define WS_FEAT   2921344                // 500000*64 f16 feature rows (64 MB)
#define WS_NEED   (WS_FEAT + (size_t)NPTS * COUT * 2)

#define PT_BLOCKS ((NPTS + 255) / 256)   // 1954 (aux kernel, 256 thr)
#define MB_BLOCKS ((NPTS + 511) / 512)   // 977  (main kernel, 512 thr)

#define W_HALFS   18432                  // (28+8) frags * 64 lanes * 8 halfs
#define W1_FRAGS  28                     // 7 k-steps * 4 ch-tiles

typedef _Float16 f16x8 __attribute__((ext_vector_type(8)));
typedef _Float16 f16x2 __attribute__((ext_vector_type(2)));
typedef float    f32x4 __attribute__((ext_vector_type(4)));

__device__ __forceinline__ f16x2 pk2(float a, float b) {
    auto r = __builtin_amdgcn_cvt_pkrtz(a, b);   // v_cvt_pkrtz_f16_f32
    union { decltype(r) x; f16x2 y; } u; u.x = r;
    return u.y;
}

__device__ __forceinline__ int cell_index(float v) {
    float nf = fminf(fmaxf((v + 1.0f) * 0.5f, 0.0f), 1.0f);
    int i = (int)floorf(nf * 256.0f);
    return i > 255 ? 255 : i;
}

__device__ __forceinline__ int flat_of(const float* pos, int p, int a1, int a2) {
    float pa1 = pos[p * 3 + a1];
    float pa2 = pos[p * 3 + a2];
    return cell_index(pa1) * GRID_W + cell_index(pa2);
}

// K0: fused weight-pack (frag order) + histogram + packed (cell,lrank) ids.
// atomicAdd's return value IS the per-cell local rank -> no scatter kernel.
__global__ void pack_hist_kernel(const float* __restrict__ W1,
                                 const float* __restrict__ W2,
                                 const float* __restrict__ pos,
                                 const int* __restrict__ ax1p,
                                 const int* __restrict__ ax2p,
                                 _Float16* __restrict__ wpk,
                                 unsigned int* __restrict__ hist,
                                 unsigned int* __restrict__ cr32)
{
    int i = blockIdx.x * 256 + threadIdx.x;
    if (i < W_HALFS) {
        int j = i & 7, lane = (i >> 3) & 63, f = i >> 9;
        int k  = ((f < W1_FRAGS) ? (f >> 2) : ((f - W1_FRAGS) >> 2)) * 32 + ((lane >> 4) << 3) + j;
        int ch = (f & 3) * 16 + (lane & 15);
        float v;
        if (f < W1_FRAGS) v = (k < 208) ? W1[k * 64 + ch] : 0.0f;
        else              v = W2[k * 64 + ch];
        wpk[i] = (_Float16)v;
    }
    if (i < NPTS) {
        int flat = flat_of(pos, i, ax1p[0], ax2p[0]);
        unsigned int old = atomicAdd(&hist[flat], 1u);
        if (cr32) cr32[i] = (unsigned int)flat | (old << 16);
    }
}

// K1: single-block exclusive scan of hist -> starts (64 cells per thread).
// ~768 KB of L2-hot traffic through one CU; replaces 3 launches.
__global__ __launch_bounds__(1024)
void scan_fused_kernel(const unsigned int* __restrict__ hist,
                       unsigned int* __restrict__ starts)
{
    __shared__ unsigned int ssum[1024];
    const int t = threadIdx.x;
    const int base = t * 64;
    unsigned int s = 0;
    #pragma unroll
    for (int i = 0; i < 64; i += 4) {
        uint4 q = *(const uint4*)(hist + base + i);
        s += q.x + q.y + q.z + q.w;
    }
    ssum[t] = s;
    __syncthreads();
    for (int off = 1; off < 1024; off <<= 1) {
        unsigned int add = (t >= off) ? ssum[t - off] : 0u;
        __syncthreads();
        ssum[t] += add;
        __syncthreads();
    }
    unsigned int run = ssum[t] - s;   // exclusive prefix of this chunk
    #pragma unroll
    for (int i = 0; i < 64; i += 4) {
        uint4 q = *(const uint4*)(hist + base + i);
        starts[base + i + 0] = run; run += q.x;
        starts[base + i + 1] = run; run += q.y;
        starts[base + i + 2] = run; run += q.z;
        starts[base + i + 3] = run; run += q.w;
    }
}

// K2: MFMA MLP, swapped operands (weights = A-frag, generated X^T = B-frag).
// D is channel-major: lane (g,n) holds channels {16c+4g+r} of point n.
// 2 tiles per pass (acc[2][4] = 32 acc regs). Single-buffer PS: LDS = 53248 B
// -> 3 blocks/CU (159.7 KB of 160 KB). launch_bounds(512,4) = 128-reg budget
// (NO spills; (512,6)'s 85-reg cap was a 1.2 GB-scratch disaster in round 2).
__global__ __launch_bounds__(512, 4)
void mlp_mfma_kernel(const float* __restrict__ pos,
                     const float* __restrict__ feats,
                     const _Float16* __restrict__ wpk,
                     const float* __restrict__ b1,
                     const float* __restrict__ ln_g,
                     const float* __restrict__ ln_b,
                     const int*   __restrict__ ax1p,
                     const int*   __restrict__ ax2p,
                     const unsigned int* __restrict__ cr32,
                     const unsigned int* __restrict__ starts,
                     _Float16* __restrict__ featbuf,
                     float* __restrict__ out,
                     int use_feat)
{
    __shared__ __align__(16) _Float16 WF[W_HALFS];   // 36864 B
    __shared__ __align__(16) _Float16 PS[8 * 1024];  // 16384 B (2 KB per wave)

    // stage frag-packed weights (coalesced 16B copies)
    {
        const uint4* src = (const uint4*)wpk;
        uint4* dst = (uint4*)WF;
        for (int i = threadIdx.x; i < W_HALFS / 8; i += 512) dst[i] = src[i];
    }

    const int lane = threadIdx.x & 63;
    const int wv   = threadIdx.x >> 6;
    const int g    = lane >> 4;        // quad
    const int n    = lane & 15;        // point-within-tile (B-col / D-col)
    char* Pw = (char*)(PS + wv * 1024);            // 2048 B per wave
    const unsigned sw = (unsigned)((n & 7) << 4);  // XOR swizzle (byte, 16B unit)

    const int wbase = blockIdx.x * 512 + wv * 64;

    // lane-constant PE base frequency: f0 = (8g+16)&31 for every s
    const float base  = 1.57079632679489662f *
                        exp2f((float)((8 * g + 16) & 31) * 0.03125f);
    const float RSTEP = 1.02189714865411668f;    // 2^(1/32)
    const float PI2   = 1.57079632679489662f;

    __syncthreads();   // WF visible

    #pragma unroll 1
    for (int tp = 0; tp < 2; ++tp) {
        // ---- load 2 tiles' point data -------------------------------------
        float px[2], py[2], pz[2];
        f16x8 fH[2];
        #pragma unroll
        for (int u = 0; u < 2; ++u) {
            const int st = wbase + (tp * 2 + u) * 16 + n;
            const int p  = (st < NPTS) ? st : 0;
            px[u] = pos[3 * p + 0];
            py[u] = pos[3 * p + 1];
            pz[u] = pos[3 * p + 2];
            if (g < 2) {
                const float4* fr = (const float4*)(feats + (size_t)p * CIN + g * 8);
                float4 fa = fr[0], fb = fr[1];
                union { f16x8 v; f16x2 h[4]; } Uf;
                Uf.h[0] = pk2(fa.x, fa.y); Uf.h[1] = pk2(fa.z, fa.w);
                Uf.h[2] = pk2(fb.x, fb.y); Uf.h[3] = pk2(fb.z, fb.w);
                fH[u] = Uf.v;
            }
        }

        // ---- GEMM1: acc[u][c] = H[ch 16c+4g+r][point n], K = 224 ----------
        f32x4 acc[2][4];
        #pragma unroll
        for (int u = 0; u < 2; ++u)
            #pragma unroll
            for (int c = 0; c < 4; ++c)
                acc[u][c] = (f32x4){0.0f, 0.0f, 0.0f, 0.0f};

        #pragma unroll
        for (int s = 0; s < 7; ++s) {
            f16x8 U[2];
            const int k0 = s * 32 + g * 8;
            if (s == 0 && g < 2) {               // feats (pre-packed)
                U[0] = fH[0]; U[1] = fH[1];
            } else if (k0 >= 208) {              // zero pad (s==6, g>=2)
                union { f16x8 v; f16x2 h[4]; } Z;
                #pragma unroll
                for (int q = 0; q < 4; ++q) Z.h[q] = pk2(0.0f, 0.0f);
                U[0] = Z.v; U[1] = Z.v;
            } else {                             // PE: sin with phase in FMA chain
                const int   e    = k0 - 16;
                const float off  = (e & 32) ? PI2 : 0.0f;
                const float offc = (e & 32) ? (PI2 * (1.0f - RSTEP)) : 0.0f;
                #pragma unroll
                for (int u = 0; u < 2; ++u) {
                    const float pv = (e < 64) ? px[u] : ((e < 128) ? py[u] : pz[u]);
                    float a = fmaf(pv, base, off);
                    union { f16x8 v; f16x2 h[4]; } G;
                    #pragma unroll
                    for (int q = 0; q < 4; ++q) {
                        float v0 = __sinf(a); a = fmaf(a, RSTEP, offc);
                        float v1 = __sinf(a); a = fmaf(a, RSTEP, offc);
                        G.h[q] = pk2(v0, v1);
                    }
                    U[u] = G.v;
                }
            }
            #pragma unroll
            for (int c = 0; c < 4; ++c) {
                f16x8 af = ((const f16x8*)WF)[(s * 4 + c) * 64 + lane];
                acc[0][c] = __builtin_amdgcn_mfma_f32_16x16x32_f16(af, U[0], acc[0][c], 0, 0, 0);
                acc[1][c] = __builtin_amdgcn_mfma_f32_16x16x32_f16(af, U[1], acc[1][c], 0, 0, 0);
            }
        }

        // ---- per tile: LN + GELU -> Pw, GEMM2, store ----------------------
        #pragma unroll
        for (int u = 0; u < 2; ++u) {
            // LN stats (lane-local 16 + 2 shuffles)
            float s1 = 0.0f, s2 = 0.0f;
            #pragma unroll
            for (int c = 0; c < 4; ++c) {
                f32x4 b1q = *(const f32x4*)(b1 + 16 * c + 4 * g);
                #pragma unroll
                for (int r = 0; r < 4; ++r) {
                    float x = acc[u][c][r] + b1q[r];
                    acc[u][c][r] = x;
                    s1 += x; s2 += x * x;
                }
            }
            s1 += __shfl_xor(s1, 16); s2 += __shfl_xor(s2, 16);
            s1 += __shfl_xor(s1, 32); s2 += __shfl_xor(s2, 32);
            const float mu   = s1 * (1.0f / 64.0f);
            const float var  = s2 * (1.0f / 64.0f) - mu * mu;
            const float rstd = __builtin_amdgcn_rsqf(var + 1e-5f);

            // GELU -> Pw (b64 swizzled writes)
            #pragma unroll
            for (int c = 0; c < 4; ++c) {
                f32x4 gq = *(const f32x4*)(ln_g + 16 * c + 4 * g);
                f32x4 bq = *(const f32x4*)(ln_b + 16 * c + 4 * g);
                float gv[4];
                #pragma unroll
                for (int r = 0; r < 4; ++r) {
                    float x  = (acc[u][c][r] - mu) * rstd * gq[r] + bq[r];
                    float w  = x * (0.7978845608028654f + 0.0356774081363001f * x * x);
                    float e2 = __expf(2.0f * w);
                    float th = 1.0f - 2.0f * __builtin_amdgcn_rcpf(e2 + 1.0f);
                    gv[r] = 0.5f * x * (1.0f + th);
                }
                union { f16x2 h[2]; uint2 u2; } W;
                W.h[0] = pk2(gv[0], gv[1]);
                W.h[1] = pk2(gv[2], gv[3]);
                *(uint2*)(Pw + n * 128 + (((unsigned)(32 * c + 8 * g)) ^ sw)) = W.u2;
            }

            // GEMM2: acc2[c] = O[ch 16c+4g+r][point n]
            f32x4 acc2[4];
            #pragma unroll
            for (int c = 0; c < 4; ++c) acc2[c] = (f32x4){0.0f, 0.0f, 0.0f, 0.0f};
            #pragma unroll
            for (int s = 0; s < 2; ++s) {
                f16x8 bf2 = *(const f16x8*)(Pw + n * 128 + (((unsigned)(64 * s + 16 * g)) ^ sw));
                #pragma unroll
                for (int c = 0; c < 4; ++c) {
                    f16x8 af = ((const f16x8*)WF)[(W1_FRAGS + s * 4 + c) * 64 + lane];
                    acc2[c] = __builtin_amdgcn_mfma_f32_16x16x32_f16(af, bf2, acc2[c], 0, 0, 0);
                }
            }

            if (use_feat) {
                // stage D2 -> Pw (b64 swizzled), then full-line scattered stores
                #pragma unroll
                for (int c = 0; c < 4; ++c) {
                    union { f16x2 h[2]; uint2 u2; } W;
                    W.h[0] = pk2(acc2[c][0], acc2[c][1]);
                    W.h[1] = pk2(acc2[c][2], acc2[c][3]);
                    *(uint2*)(Pw + n * 128 + (((unsigned)(32 * c + 8 * g)) ^ sw)) = W.u2;
                }
                // 8 lanes per row x 16B: each store covers a full 128B line.
                // dst slot = starts[cell] + lrank, both cache-hot broadcasts.
                #pragma unroll
                for (int h = 0; h < 2; ++h) {
                    const int row = h * 8 + (lane >> 3);
                    const int gs  = wbase + (tp * 2 + u) * 16 + row;
                    if (gs < NPTS) {
                        const unsigned cr  = cr32[gs];
                        const unsigned dst = starts[cr & 0xFFFFu] + (cr >> 16);
                        const uint4 v = *(const uint4*)(Pw + row * 128 +
                            (((unsigned)((lane & 7) * 16)) ^ ((unsigned)((row & 7) << 4))));
                        *(uint4*)(featbuf + (size_t)dst * COUT + (lane & 7) * 8) = v;
                    }
                }
            } else {
                // fallback: direct fp32 atomics (correctness path, not perf)
                const int st = wbase + (tp * 2 + u) * 16 + n;
                if (st < NPTS) {
                    const int cellr = flat_of(pos, st, ax1p[0], ax2p[0]);
                    #pragma unroll
                    for (int c = 0; c < 4; ++c)
                        #pragma unroll
                        for (int r = 0; r < 4; ++r)
                            unsafeAtomicAdd(&out[(size_t)(16 * c + 4 * g + r) * NCELL + cellr],
                                            acc2[c][r]);
                }
            }
        }
    }
}

// K3: per-cell dense reduce. 1 cell per wave, 4 predicated independent loads
// (no serial tail); block = 1024 thr = 16 waves = 16 cells; 4096 blocks.
__global__ __launch_bounds__(1024)
void reduce_kernel(const _Float16* __restrict__ featbuf,
                   const unsigned int* __restrict__ starts,
                   const unsigned int* __restrict__ hist,
                   const float* __restrict__ b2,
                   float* __restrict__ out)
{
    __shared__ float R[16][66];
    const int lane  = threadIdx.x & 63;
    const int wv    = threadIdx.x >> 6;    // 0..15 = cell-within-block
    const int cbase = blockIdx.x * 16;
    const float b2v = b2[lane];

    const int cell = cbase + wv;
    const unsigned int s0  = starts[cell];
    const unsigned int cnt = hist[cell];

    float a0 = 0.0f, a1 = 0.0f, a2 = 0.0f, a3 = 0.0f;
    for (unsigned int k = 0; k < cnt; k += 4) {
        unsigned int i0 = s0 + k;
        unsigned int i1 = i0 + 1 < (unsigned)NPTS ? i0 + 1 : (unsigned)(NPTS - 1);
        unsigned int i2 = i0 + 2 < (unsigned)NPTS ? i0 + 2 : (unsigned)(NPTS - 1);
        unsigned int i3 = i0 + 3 < (unsigned)NPTS ? i0 + 3 : (unsigned)(NPTS - 1);
        float v0 = (float)featbuf[(size_t)i0 * COUT + lane];
        float v1 = (float)featbuf[(size_t)i1 * COUT + lane];
        float v2 = (float)featbuf[(size_t)i2 * COUT + lane];
        float v3 = (float)featbuf[(size_t)i3 * COUT + lane];
        a0 += v0;
        a1 += (k + 1 < cnt) ? v1 : 0.0f;
        a2 += (k + 2 < cnt) ? v2 : 0.0f;
        a3 += (k + 3 < cnt) ? v3 : 0.0f;
    }
    float m = (a0 + a1) + (a2 + a3);
    R[wv][lane] = m / fmaxf((float)cnt, 1.0f) + (cnt ? b2v : 0.0f);
    __syncthreads();

    // store: thread t -> out[ch = t>>4][cbase + (t&15)]; 64B contiguous per ch
    const int ch = threadIdx.x >> 4;
    const int ci = threadIdx.x & 15;
    out[ch * NCELL + cbase + ci] = R[ci][ch];
}

// K4 (fallback only): divide by counts + add b2 (guarded for empty cells)
__global__ void finalize_kernel(float* __restrict__ out,
                                const unsigned int* __restrict__ hist,
                                const float* __restrict__ b2)
{
    int t = blockIdx.x * 256 + threadIdx.x;
    int cell = t & (NCELL - 1);
    int ch   = t >> 16;
    float c  = (float)hist[cell];
    out[t] = out[t] / fmaxf(c, 1.0f) + ((c > 0.0f) ? b2[ch] : 0.0f);
}

extern "C" void kernel_launch(void* const* d_in, const int* in_sizes, int n_in,
                              void* d_out, int out_size, void* d_ws, size_t ws_size,
                              hipStream_t stream) {
    (void)in_sizes; (void)n_in; (void)out_size;
    const float* pos   = (const float*)d_in[0];
    const float* feats = (const float*)d_in[1];
    const float* W1    = (const float*)d_in[2];
    const float* b1    = (const float*)d_in[3];
    const float* ln_g  = (const float*)d_in[4];
    const float* ln_b  = (const float*)d_in[5];
    const float* W2    = (const float*)d_in[6];
    const float* b2    = (const float*)d_in[7];
    const int*   ax1   = (const int*)d_in[8];
    const int*   ax2   = (const int*)d_in[9];

    char* ws = (char*)d_ws;
    unsigned int* hist   = (unsigned int*)(ws + WS_HIST);
    unsigned int* starts = (unsigned int*)(ws + WS_STARTS);
    unsigned int* cr32   = (unsigned int*)(ws + WS_CR);
    _Float16*     wpk    = (_Float16*)(ws + WS_WPK);
    _Float16*     featbf = (_Float16*)(ws + WS_FEAT);

    float* out = (float*)d_out;
    const int use_feat = (ws_size >= WS_NEED) ? 1 : 0;

    hipMemsetAsync(hist, 0, NCELL * sizeof(unsigned int), stream);
    if (!use_feat)
        hipMemsetAsync(d_out, 0, (size_t)COUT * NCELL * sizeof(float), stream);

    pack_hist_kernel<<<PT_BLOCKS, 256, 0, stream>>>(
        W1, W2, pos, ax1, ax2, wpk, hist,
        use_feat ? cr32 : (unsigned int*)nullptr);
    if (use_feat)
        scan_fused_kernel<<<1, 1024, 0, stream>>>(hist, starts);
    mlp_mfma_kernel<<<MB_BLOCKS, 512, 0, stream>>>(
        pos, feats, wpk, b1, ln_g, ln_b, ax1, ax2, cr32, starts, featbf, out, use_feat);
    if (use_feat)
        reduce_kernel<<<NCELL / 16, 1024, 0, stream>>>(featbf, starts, hist, b2, out);
    else
        finalize_kernel<<<(COUT * NCELL) / 256, 256, 0, stream>>>(out, hist, b2);
}

// Round 5
// 226.881 us; speedup vs baseline: 1.0240x; 1.0240x over previous
//
#include <hip/hip_runtime.h>
#include <math.h>

// Problem constants (reference file)
#define NPTS   500000
#define CIN    16
#define COUT   64
#define GRID_W 256
#define NCELL  65536

// ws layout (bytes)
#define WS_HIST   0                      // 65536 u32  (256 KB)
#define WS_STARTS 262144                 // 65536 u32 segment starts (256 KB)
#define WS_CR     524288                 // 500000 u32 (cell | lrank<<16) (2 MB)
#define WS_SORT   2621440                // 500000 i32 sorted point ids (2 MB)
#define WS_WPK    4718592                // 18432 f16 frag-packed weights (36864 B)
#define WS_FEAT   4755456                // 500000*64 f16 feature rows (64 MB)
#define WS_NEED   (WS_FEAT + (size_t)NPTS * COUT * 2)

#define PT_BLOCKS ((NPTS + 255) / 256)   // 1954 (aux kernels, 256 thr)
#define MB_BLOCKS ((NPTS + 511) / 512)   // 977  (main kernel, 512 thr)

#define W_HALFS   18432                  // (28+8) frags * 64 lanes * 8 halfs
#define W1_FRAGS  28                     // 7 k-steps * 4 ch-tiles

typedef _Float16 f16x8 __attribute__((ext_vector_type(8)));
typedef _Float16 f16x2 __attribute__((ext_vector_type(2)));
typedef float    f32x4 __attribute__((ext_vector_type(4)));

__device__ __forceinline__ f16x2 pk2(float a, float b) {
    auto r = __builtin_amdgcn_cvt_pkrtz(a, b);   // v_cvt_pkrtz_f16_f32
    union { decltype(r) x; f16x2 y; } u; u.x = r;
    return u.y;
}

// raw v_sin_f32: input in REVOLUTIONS (|x| < 1 here, no range reduction needed)
__device__ __forceinline__ float vsin(float x) {
    float r;
    asm("v_sin_f32 %0, %1" : "=v"(r) : "v"(x));
    return r;
}

__device__ __forceinline__ int cell_index(float v) {
    float nf = fminf(fmaxf((v + 1.0f) * 0.5f, 0.0f), 1.0f);
    int i = (int)floorf(nf * 256.0f);
    return i > 255 ? 255 : i;
}

__device__ __forceinline__ int flat_of(const float* pos, int p, int a1, int a2) {
    float pa1 = pos[p * 3 + a1];
    float pa2 = pos[p * 3 + a2];
    return cell_index(pa1) * GRID_W + cell_index(pa2);
}

// K0: fused weight-pack (frag order) + histogram + packed (cell,lrank) ids.
__global__ void pack_hist_kernel(const float* __restrict__ W1,
                                 const float* __restrict__ W2,
                                 const float* __restrict__ pos,
                                 const int* __restrict__ ax1p,
                                 const int* __restrict__ ax2p,
                                 _Float16* __restrict__ wpk,
                                 unsigned int* __restrict__ hist,
                                 unsigned int* __restrict__ cr32)
{
    int i = blockIdx.x * 256 + threadIdx.x;
    if (i < W_HALFS) {
        int j = i & 7, lane = (i >> 3) & 63, f = i >> 9;
        int k  = ((f < W1_FRAGS) ? (f >> 2) : ((f - W1_FRAGS) >> 2)) * 32 + ((lane >> 4) << 3) + j;
        int ch = (f & 3) * 16 + (lane & 15);
        float v;
        if (f < W1_FRAGS) v = (k < 208) ? W1[k * 64 + ch] : 0.0f;
        else              v = W2[k * 64 + ch];
        wpk[i] = (_Float16)v;
    }
    if (i < NPTS) {
        int flat = flat_of(pos, i, ax1p[0], ax2p[0]);
        unsigned int old = atomicAdd(&hist[flat], 1u);
        if (cr32) cr32[i] = (unsigned int)flat | (old << 16);
    }
}

// K1: single-block exclusive scan of hist -> starts (64 cells per thread).
__global__ __launch_bounds__(1024)
void scan_fused_kernel(const unsigned int* __restrict__ hist,
                       unsigned int* __restrict__ starts)
{
    __shared__ unsigned int ssum[1024];
    const int t = threadIdx.x;
    const int base = t * 64;
    unsigned int s = 0;
    #pragma unroll
    for (int i = 0; i < 64; i += 4) {
        uint4 q = *(const uint4*)(hist + base + i);
        s += q.x + q.y + q.z + q.w;
    }
    ssum[t] = s;
    __syncthreads();
    for (int off = 1; off < 1024; off <<= 1) {
        unsigned int add = (t >= off) ? ssum[t - off] : 0u;
        __syncthreads();
        ssum[t] += add;
        __syncthreads();
    }
    unsigned int run = ssum[t] - s;   // exclusive prefix of this chunk
    #pragma unroll
    for (int i = 0; i < 64; i += 4) {
        uint4 q = *(const uint4*)(hist + base + i);
        starts[base + i + 0] = run; run += q.x;
        starts[base + i + 1] = run; run += q.y;
        starts[base + i + 2] = run; run += q.z;
        starts[base + i + 3] = run; run += q.w;
    }
}

// K2: sorted[starts[cell]+lrank] = p. Scattered 4B writes into a 2 MB target
// -> fully L2-absorbed (the cheap kind of scatter).
__global__ void build_sorted_kernel(const unsigned int* __restrict__ cr32,
                                    const unsigned int* __restrict__ starts,
                                    int* __restrict__ sorted)
{
    int p = blockIdx.x * 256 + threadIdx.x;
    if (p >= NPTS) return;
    unsigned int cr = cr32[p];
    sorted[starts[cr & 0xFFFFu] + (cr >> 16)] = p;
}

// K3: MFMA MLP, swapped operands (weights = A-frag, generated X^T = B-frag).
// D is channel-major: lane (g,n) holds channels {16c+4g+r} of point n.
// Epilogue: DENSE register->global row writes to featbuf[point] (fully
// coalesced sequential HBM); rank indirection moved to the reduce's gather.
__global__ __launch_bounds__(512, 4)
void mlp_mfma_kernel(const float* __restrict__ pos,
                     const float* __restrict__ feats,
                     const _Float16* __restrict__ wpk,
                     const float* __restrict__ b1,
                     const float* __restrict__ ln_g,
                     const float* __restrict__ ln_b,
                     const int*   __restrict__ ax1p,
                     const int*   __restrict__ ax2p,
                     _Float16* __restrict__ featbuf,
                     float* __restrict__ out,
                     int use_feat)
{
    __shared__ __align__(16) _Float16 WF[W_HALFS];   // 36864 B
    __shared__ __align__(16) _Float16 PS[8 * 1024];  // 16384 B (2 KB per wave)

    // stage frag-packed weights (coalesced 16B copies)
    {
        const uint4* src = (const uint4*)wpk;
        uint4* dst = (uint4*)WF;
        for (int i = threadIdx.x; i < W_HALFS / 8; i += 512) dst[i] = src[i];
    }

    const int lane = threadIdx.x & 63;
    const int wv   = threadIdx.x >> 6;
    const int g    = lane >> 4;        // quad
    const int n    = lane & 15;        // point-within-tile (B-col / D-col)
    char* Pw = (char*)(PS + wv * 1024);            // 2048 B per wave
    const unsigned sw = (unsigned)((n & 7) << 4);  // XOR swizzle (byte, 16B unit)

    const int wbase = blockIdx.x * 512 + wv * 64;

    // lane-constant PE base frequency IN REVOLUTIONS: 0.25 * 2^(f0/32)
    const float base  = 0.25f * exp2f((float)((8 * g + 16) & 31) * 0.03125f);
    const float RSTEP = 1.02189714865411668f;    // 2^(1/32)

    __syncthreads();   // WF visible

    #pragma unroll 1
    for (int tp = 0; tp < 2; ++tp) {
        // ---- load 2 tiles' point data -------------------------------------
        float px[2], py[2], pz[2];
        f16x8 fH[2];
        #pragma unroll
        for (int u = 0; u < 2; ++u) {
            const int st = wbase + (tp * 2 + u) * 16 + n;
            const int p  = (st < NPTS) ? st : 0;
            px[u] = pos[3 * p + 0];
            py[u] = pos[3 * p + 1];
            pz[u] = pos[3 * p + 2];
            if (g < 2) {
                const float4* fr = (const float4*)(feats + (size_t)p * CIN + g * 8);
                float4 fa = fr[0], fb = fr[1];
                union { f16x8 v; f16x2 h[4]; } Uf;
                Uf.h[0] = pk2(fa.x, fa.y); Uf.h[1] = pk2(fa.z, fa.w);
                Uf.h[2] = pk2(fb.x, fb.y); Uf.h[3] = pk2(fb.z, fb.w);
                fH[u] = Uf.v;
            }
        }

        // ---- GEMM1: acc[u][c] = H[ch 16c+4g+r][point n], K = 224 ----------
        f32x4 acc[2][4];
        #pragma unroll
        for (int u = 0; u < 2; ++u)
            #pragma unroll
            for (int c = 0; c < 4; ++c)
                acc[u][c] = (f32x4){0.0f, 0.0f, 0.0f, 0.0f};

        #pragma unroll
        for (int s = 0; s < 7; ++s) {
            f16x8 U[2];
            const int k0 = s * 32 + g * 8;
            if (s == 0 && g < 2) {               // feats (pre-packed)
                U[0] = fH[0]; U[1] = fH[1];
            } else if (k0 >= 208) {              // zero pad (s==6, g>=2)
                union { f16x8 v; f16x2 h[4]; } Z;
                #pragma unroll
                for (int q = 0; q < 4; ++q) Z.h[q] = pk2(0.0f, 0.0f);
                U[0] = Z.v; U[1] = Z.v;
            } else {                             // PE: v_sin in revolutions
                const int   e    = k0 - 16;
                const float off  = (e & 32) ? 0.25f : 0.0f;
                const float offc = (e & 32) ? (0.25f * (1.0f - RSTEP)) : 0.0f;
                #pragma unroll
                for (int u = 0; u < 2; ++u) {
                    const float pv = (e < 64) ? px[u] : ((e < 128) ? py[u] : pz[u]);
                    float a = fmaf(pv, base, off);
                    union { f16x8 v; f16x2 h[4]; } G;
                    #pragma unroll
                    for (int q = 0; q < 4; ++q) {
                        float v0 = vsin(a); a = fmaf(a, RSTEP, offc);
                        float v1 = vsin(a); a = fmaf(a, RSTEP, offc);
                        G.h[q] = pk2(v0, v1);
                    }
                    U[u] = G.v;
                }
            }
            #pragma unroll
            for (int c = 0; c < 4; ++c) {
                f16x8 af = ((const f16x8*)WF)[(s * 4 + c) * 64 + lane];
                acc[0][c] = __builtin_amdgcn_mfma_f32_16x16x32_f16(af, U[0], acc[0][c], 0, 0, 0);
                acc[1][c] = __builtin_amdgcn_mfma_f32_16x16x32_f16(af, U[1], acc[1][c], 0, 0, 0);
            }
        }

        // ---- per tile: LN + GELU -> Pw, GEMM2, dense store ----------------
        #pragma unroll
        for (int u = 0; u < 2; ++u) {
            // LN stats (lane-local 16 + 2 shuffles)
            float s1 = 0.0f, s2 = 0.0f;
            #pragma unroll
            for (int c = 0; c < 4; ++c) {
                f32x4 b1q = *(const f32x4*)(b1 + 16 * c + 4 * g);
                #pragma unroll
                for (int r = 0; r < 4; ++r) {
                    float x = acc[u][c][r] + b1q[r];
                    acc[u][c][r] = x;
                    s1 += x; s2 += x * x;
                }
            }
            s1 += __shfl_xor(s1, 16); s2 += __shfl_xor(s2, 16);
            s1 += __shfl_xor(s1, 32); s2 += __shfl_xor(s2, 32);
            const float mu   = s1 * (1.0f / 64.0f);
            const float var  = s2 * (1.0f / 64.0f) - mu * mu;
            const float rstd = __builtin_amdgcn_rsqf(var + 1e-5f);

            // GELU via x*sigmoid(2u) (exact identity with tanh form) -> Pw
            #pragma unroll
            for (int c = 0; c < 4; ++c) {
                f32x4 gq = *(const f32x4*)(ln_g + 16 * c + 4 * g);
                f32x4 bq = *(const f32x4*)(ln_b + 16 * c + 4 * g);
                float gv[4];
                #pragma unroll
                for (int r = 0; r < 4; ++r) {
                    float x  = (acc[u][c][r] - mu) * rstd * gq[r] + bq[r];
                    float w  = x * (0.7978845608028654f + 0.0356774081363001f * x * x);
                    float e2 = __expf(w + w);
                    gv[r] = x * e2 * __builtin_amdgcn_rcpf(e2 + 1.0f);
                }
                union { f16x2 h[2]; uint2 u2; } W;
                W.h[0] = pk2(gv[0], gv[1]);
                W.h[1] = pk2(gv[2], gv[3]);
                *(uint2*)(Pw + n * 128 + (((unsigned)(32 * c + 8 * g)) ^ sw)) = W.u2;
            }

            // GEMM2: acc2[c] = O[ch 16c+4g+r][point n]
            f32x4 acc2[4];
            #pragma unroll
            for (int c = 0; c < 4; ++c) acc2[c] = (f32x4){0.0f, 0.0f, 0.0f, 0.0f};
            #pragma unroll
            for (int s = 0; s < 2; ++s) {
                f16x8 bf2 = *(const f16x8*)(Pw + n * 128 + (((unsigned)(64 * s + 16 * g)) ^ sw));
                #pragma unroll
                for (int c = 0; c < 4; ++c) {
                    f16x8 af = ((const f16x8*)WF)[(W1_FRAGS + s * 4 + c) * 64 + lane];
                    acc2[c] = __builtin_amdgcn_mfma_f32_16x16x32_f16(af, bf2, acc2[c], 0, 0, 0);
                }
            }

            if (use_feat) {
                // DENSE row write straight from registers: lane (g,n) owns
                // channels 16c+4g..16c+4g+3 of point (wbase + tile*16 + n).
                // Wave covers 16 consecutive rows = 2 KB contiguous.
                const int gs = wbase + (tp * 2 + u) * 16 + n;
                if (gs < NPTS) {
                    _Float16* dstp = featbuf + (size_t)gs * COUT + 4 * g;
                    #pragma unroll
                    for (int c = 0; c < 4; ++c) {
                        union { f16x2 h[2]; uint2 u2; } W;
                        W.h[0] = pk2(acc2[c][0], acc2[c][1]);
                        W.h[1] = pk2(acc2[c][2], acc2[c][3]);
                        *(uint2*)(dstp + 16 * c) = W.u2;
                    }
                }
            } else {
                // fallback: direct fp32 atomics (correctness path, not perf)
                const int st = wbase + (tp * 2 + u) * 16 + n;
                if (st < NPTS) {
                    const int cellr = flat_of(pos, st, ax1p[0], ax2p[0]);
                    #pragma unroll
                    for (int c = 0; c < 4; ++c)
                        #pragma unroll
                        for (int r = 0; r < 4; ++r)
                            unsafeAtomicAdd(&out[(size_t)(16 * c + 4 * g + r) * NCELL + cellr],
                                            acc2[c][r]);
                }
            }
        }
    }
}

// K4: per-cell reduce with GATHER: row p = sorted[s0+k], featbuf[p] is
// L3-resident (just written, 64 MB < 256 MB). 1 cell per wave, 4 predicated
// independent chains; block = 1024 thr = 16 waves = 16 cells; 4096 blocks.
__global__ __launch_bounds__(1024)
void reduce_kernel(const _Float16* __restrict__ featbuf,
                   const int* __restrict__ sorted,
                   const unsigned int* __restrict__ starts,
                   const unsigned int* __restrict__ hist,
                   const float* __restrict__ b2,
                   float* __restrict__ out)
{
    __shared__ float R[16][66];
    const int lane  = threadIdx.x & 63;
    const int wv    = threadIdx.x >> 6;    // 0..15 = cell-within-block
    const int cbase = blockIdx.x * 16;
    const float b2v = b2[lane];

    const int cell = cbase + wv;
    const unsigned int s0  = starts[cell];
    const unsigned int cnt = hist[cell];

    float a0 = 0.0f, a1 = 0.0f, a2 = 0.0f, a3 = 0.0f;
    for (unsigned int k = 0; k < cnt; k += 4) {
        unsigned int i0 = s0 + k;
        unsigned int i1 = i0 + 1 < (unsigned)NPTS ? i0 + 1 : (unsigned)(NPTS - 1);
        unsigned int i2 = i0 + 2 < (unsigned)NPTS ? i0 + 2 : (unsigned)(NPTS - 1);
        unsigned int i3 = i0 + 3 < (unsigned)NPTS ? i0 + 3 : (unsigned)(NPTS - 1);
        int r0 = sorted[i0];
        int r1 = sorted[i1];
        int r2 = sorted[i2];
        int r3 = sorted[i3];
        float v0 = (float)featbuf[(size_t)r0 * COUT + lane];
        float v1 = (float)featbuf[(size_t)r1 * COUT + lane];
        float v2 = (float)featbuf[(size_t)r2 * COUT + lane];
        float v3 = (float)featbuf[(size_t)r3 * COUT + lane];
        a0 += v0;
        a1 += (k + 1 < cnt) ? v1 : 0.0f;
        a2 += (k + 2 < cnt) ? v2 : 0.0f;
        a3 += (k + 3 < cnt) ? v3 : 0.0f;
    }
    float m = (a0 + a1) + (a2 + a3);
    R[wv][lane] = m / fmaxf((float)cnt, 1.0f) + (cnt ? b2v : 0.0f);
    __syncthreads();

    // store: thread t -> out[ch = t>>4][cbase + (t&15)]; 64B contiguous per ch
    const int ch = threadIdx.x >> 4;
    const int ci = threadIdx.x & 15;
    out[ch * NCELL + cbase + ci] = R[ci][ch];
}

// K5 (fallback only): divide by counts + add b2 (guarded for empty cells)
__global__ void finalize_kernel(float* __restrict__ out,
                                const unsigned int* __restrict__ hist,
                                const float* __restrict__ b2)
{
    int t = blockIdx.x * 256 + threadIdx.x;
    int cell = t & (NCELL - 1);
    int ch   = t >> 16;
    float c  = (float)hist[cell];
    out[t] = out[t] / fmaxf(c, 1.0f) + ((c > 0.0f) ? b2[ch] : 0.0f);
}

extern "C" void kernel_launch(void* const* d_in, const int* in_sizes, int n_in,
                              void* d_out, int out_size, void* d_ws, size_t ws_size,
                              hipStream_t stream) {
    (void)in_sizes; (void)n_in; (void)out_size;
    const float* pos   = (const float*)d_in[0];
    const float* feats = (const float*)d_in[1];
    const float* W1    = (const float*)d_in[2];
    const float* b1    = (const float*)d_in[3];
    const float* ln_g  = (const float*)d_in[4];
    const float* ln_b  = (const float*)d_in[5];
    const float* W2    = (const float*)d_in[6];
    const float* b2    = (const float*)d_in[7];
    const int*   ax1   = (const int*)d_in[8];
    const int*   ax2   = (const int*)d_in[9];

    char* ws = (char*)d_ws;
    unsigned int* hist   = (unsigned int*)(ws + WS_HIST);
    unsigned int* starts = (unsigned int*)(ws + WS_STARTS);
    unsigned int* cr32   = (unsigned int*)(ws + WS_CR);
    int*          sorted = (int*)(ws + WS_SORT);
    _Float16*     wpk    = (_Float16*)(ws + WS_WPK);
    _Float16*     featbf = (_Float16*)(ws + WS_FEAT);

    float* out = (float*)d_out;
    const int use_feat = (ws_size >= WS_NEED) ? 1 : 0;

    hipMemsetAsync(hist, 0, NCELL * sizeof(unsigned int), stream);
    if (!use_feat)
        hipMemsetAsync(d_out, 0, (size_t)COUT * NCELL * sizeof(float), stream);

    pack_hist_kernel<<<PT_BLOCKS, 256, 0, stream>>>(
        W1, W2, pos, ax1, ax2, wpk, hist,
        use_feat ? cr32 : (unsigned int*)nullptr);
    if (use_feat) {
        scan_fused_kernel<<<1, 1024, 0, stream>>>(hist, starts);
        build_sorted_kernel<<<PT_BLOCKS, 256, 0, stream>>>(cr32, starts, sorted);
    }
    mlp_mfma_kernel<<<MB_BLOCKS, 512, 0, stream>>>(
        pos, feats, wpk, b1, ln_g, ln_b, ax1, ax2, featbf, out, use_feat);
    if (use_feat)
        reduce_kernel<<<NCELL / 16, 1024, 0, stream>>>(featbf, sorted, starts, hist, b2, out);
    else
        finalize_kernel<<<(COUT * NCELL) / 256, 256, 0, stream>>>(out, hist, b2);
}

// Round 6
// 224.839 us; speedup vs baseline: 1.0333x; 1.0091x over previous
//
#include <hip/hip_runtime.h>
#include <math.h>

// Problem constants (reference file)
#define NPTS   500000
#define CIN    16
#define COUT   64
#define GRID_W 256
#define NCELL  65536

// ws layout (bytes)
#define WS_HIST   0                      // 65536 u32  (256 KB)
#define WS_STARTS 262144                 // 65536 u32 segment starts (256 KB)
#define WS_CR     524288                 // 500000 u32 (cell | lrank<<16) (2 MB)
#define WS_SORT   2621440                // 500000 i32 sorted point ids (2 MB)
#define WS_WPK    4718592                // 18432 f16 frag-packed weights (36864 B)
#define WS_FEAT   4755456                // 500000*64 f16 feature rows (64 MB)
#define WS_NEED   (WS_FEAT + (size_t)NPTS * COUT * 2)

#define PT_BLOCKS ((NPTS + 255) / 256)   // 1954 (aux kernels, 256 thr)
#define MB_BLOCKS ((NPTS + 511) / 512)   // 977  (main kernel, 512 thr)

#define W_HALFS   18432                  // (28+8) frags * 64 lanes * 8 halfs
#define W1_FRAGS  28                     // 7 k-steps * 4 ch-tiles

typedef _Float16 f16x8 __attribute__((ext_vector_type(8)));
typedef _Float16 f16x2 __attribute__((ext_vector_type(2)));
typedef float    f32x4 __attribute__((ext_vector_type(4)));

__device__ __forceinline__ f16x2 pk2(float a, float b) {
    auto r = __builtin_amdgcn_cvt_pkrtz(a, b);   // v_cvt_pkrtz_f16_f32
    union { decltype(r) x; f16x2 y; } u; u.x = r;
    return u.y;
}

// raw v_sin_f32: input in REVOLUTIONS (|x| < 1 here, no range reduction needed)
__device__ __forceinline__ float vsin(float x) {
    float r;
    asm("v_sin_f32 %0, %1" : "=v"(r) : "v"(x));
    return r;
}

__device__ __forceinline__ int cell_index(float v) {
    float nf = fminf(fmaxf((v + 1.0f) * 0.5f, 0.0f), 1.0f);
    int i = (int)floorf(nf * 256.0f);
    return i > 255 ? 255 : i;
}

// K0: tiny weight-pack (frag order) — histogram moved into the MLP kernel.
__global__ void pack_w_kernel(const float* __restrict__ W1,
                              const float* __restrict__ W2,
                              _Float16* __restrict__ wpk)
{
    int i = blockIdx.x * 256 + threadIdx.x;
    if (i >= W_HALFS) return;
    int j = i & 7, lane = (i >> 3) & 63, f = i >> 9;
    int k  = ((f < W1_FRAGS) ? (f >> 2) : ((f - W1_FRAGS) >> 2)) * 32 + ((lane >> 4) << 3) + j;
    int ch = (f & 3) * 16 + (lane & 15);
    float v;
    if (f < W1_FRAGS) v = (k < 208) ? W1[k * 64 + ch] : 0.0f;
    else              v = W2[k * 64 + ch];
    wpk[i] = (_Float16)v;
}

// K1: single-block exclusive scan of hist -> starts (64 cells per thread).
__global__ __launch_bounds__(1024)
void scan_fused_kernel(const unsigned int* __restrict__ hist,
                       unsigned int* __restrict__ starts)
{
    __shared__ unsigned int ssum[1024];
    const int t = threadIdx.x;
    const int base = t * 64;
    unsigned int s = 0;
    #pragma unroll
    for (int i = 0; i < 64; i += 4) {
        uint4 q = *(const uint4*)(hist + base + i);
        s += q.x + q.y + q.z + q.w;
    }
    ssum[t] = s;
    __syncthreads();
    for (int off = 1; off < 1024; off <<= 1) {
        unsigned int add = (t >= off) ? ssum[t - off] : 0u;
        __syncthreads();
        ssum[t] += add;
        __syncthreads();
    }
    unsigned int run = ssum[t] - s;   // exclusive prefix of this chunk
    #pragma unroll
    for (int i = 0; i < 64; i += 4) {
        uint4 q = *(const uint4*)(hist + base + i);
        starts[base + i + 0] = run; run += q.x;
        starts[base + i + 1] = run; run += q.y;
        starts[base + i + 2] = run; run += q.z;
        starts[base + i + 3] = run; run += q.w;
    }
}

// K2: sorted[starts[cell]+lrank] = p. Scattered 4B writes into a 2 MB target
// -> fully L2-absorbed (the cheap kind of scatter).
__global__ void build_sorted_kernel(const unsigned int* __restrict__ cr32,
                                    const unsigned int* __restrict__ starts,
                                    int* __restrict__ sorted)
{
    int p = blockIdx.x * 256 + threadIdx.x;
    if (p >= NPTS) return;
    unsigned int cr = cr32[p];
    sorted[starts[cr & 0xFFFFu] + (cr >> 16)] = p;
}

// K3: MFMA MLP, swapped operands (weights = A-frag, generated X^T = B-frag).
// D is channel-major: lane (g,n) holds channels {16c+4g+r} of point n.
// Also computes the cell histogram + (cell,lrank) ids inline (g==0 lanes),
// hidden under MFMA — removes the standalone pos-walking histogram kernel.
// Epilogue: DENSE register->global row writes to featbuf[point].
__global__ __launch_bounds__(512, 4)
void mlp_mfma_kernel(const float* __restrict__ pos,
                     const float* __restrict__ feats,
                     const _Float16* __restrict__ wpk,
                     const float* __restrict__ b1,
                     const float* __restrict__ ln_g,
                     const float* __restrict__ ln_b,
                     const int*   __restrict__ ax1p,
                     const int*   __restrict__ ax2p,
                     unsigned int* __restrict__ hist,
                     unsigned int* __restrict__ cr32,
                     _Float16* __restrict__ featbuf,
                     float* __restrict__ out,
                     int use_feat)
{
    __shared__ __align__(16) _Float16 WF[W_HALFS];   // 36864 B
    __shared__ __align__(16) _Float16 PS[8 * 1024];  // 16384 B (2 KB per wave)

    // stage frag-packed weights (coalesced 16B copies)
    {
        const uint4* src = (const uint4*)wpk;
        uint4* dst = (uint4*)WF;
        for (int i = threadIdx.x; i < W_HALFS / 8; i += 512) dst[i] = src[i];
    }

    const int lane = threadIdx.x & 63;
    const int wv   = threadIdx.x >> 6;
    const int g    = lane >> 4;        // quad
    const int n    = lane & 15;        // point-within-tile (B-col / D-col)
    char* Pw = (char*)(PS + wv * 1024);            // 2048 B per wave
    const unsigned sw = (unsigned)((n & 7) << 4);  // XOR swizzle (byte, 16B unit)

    const int wbase = blockIdx.x * 512 + wv * 64;
    const int a1 = ax1p[0], a2 = ax2p[0];

    // 8 independent per-lane PE base frequencies (REVOLUTIONS): breaks the
    // serial fma->sin chain; also closer to reference's exact products.
    float bases[8];
    {
        const float f0 = (float)((8 * g + 16) & 31);
        #pragma unroll
        for (int q = 0; q < 8; ++q)
            bases[q] = 0.25f * exp2f((f0 + (float)q) * 0.03125f);
    }

    __syncthreads();   // WF visible

    #pragma unroll 1
    for (int tp = 0; tp < 2; ++tp) {
        // ---- load 2 tiles' point data -------------------------------------
        float px[2], py[2], pz[2];
        f16x8 fH[2];
        #pragma unroll
        for (int u = 0; u < 2; ++u) {
            const int st = wbase + (tp * 2 + u) * 16 + n;
            const int p  = (st < NPTS) ? st : 0;
            px[u] = pos[3 * p + 0];
            py[u] = pos[3 * p + 1];
            pz[u] = pos[3 * p + 2];
            if (g < 2) {
                const float4* fr = (const float4*)(feats + (size_t)p * CIN + g * 8);
                float4 fa = fr[0], fb = fr[1];
                union { f16x8 v; f16x2 h[4]; } Uf;
                Uf.h[0] = pk2(fa.x, fa.y); Uf.h[1] = pk2(fa.z, fa.w);
                Uf.h[2] = pk2(fb.x, fb.y); Uf.h[3] = pk2(fb.z, fb.w);
                fH[u] = Uf.v;
            }
        }

        // ---- inline histogram + (cell,lrank) (g==0 lanes, hides under MFMA)
        if (g == 0) {
            #pragma unroll
            for (int u = 0; u < 2; ++u) {
                const int st = wbase + (tp * 2 + u) * 16 + n;
                if (st < NPTS) {
                    const float pa1 = (a1 == 0) ? px[u] : ((a1 == 1) ? py[u] : pz[u]);
                    const float pa2 = (a2 == 0) ? px[u] : ((a2 == 1) ? py[u] : pz[u]);
                    const int flat = cell_index(pa1) * GRID_W + cell_index(pa2);
                    const unsigned int old = atomicAdd(&hist[flat], 1u);
                    if (cr32) cr32[st] = (unsigned int)flat | (old << 16);
                }
            }
        }

        // ---- GEMM1: acc[u][c] = H[ch 16c+4g+r][point n], K = 224 ----------
        f32x4 acc[2][4];
        #pragma unroll
        for (int u = 0; u < 2; ++u)
            #pragma unroll
            for (int c = 0; c < 4; ++c)
                acc[u][c] = (f32x4){0.0f, 0.0f, 0.0f, 0.0f};

        #pragma unroll
        for (int s = 0; s < 7; ++s) {
            f16x8 U[2];
            const int k0 = s * 32 + g * 8;
            if (s == 0 && g < 2) {               // feats (pre-packed)
                U[0] = fH[0]; U[1] = fH[1];
            } else if (k0 >= 208) {              // zero pad (s==6, g>=2)
                union { f16x8 v; f16x2 h[4]; } Z;
                #pragma unroll
                for (int q = 0; q < 4; ++q) Z.h[q] = pk2(0.0f, 0.0f);
                U[0] = Z.v; U[1] = Z.v;
            } else {                             // PE: 8 independent v_sin
                const int   e   = k0 - 16;
                const float off = (e & 32) ? 0.25f : 0.0f;
                #pragma unroll
                for (int u = 0; u < 2; ++u) {
                    const float pv = (e < 64) ? px[u] : ((e < 128) ? py[u] : pz[u]);
                    float sv[8];
                    #pragma unroll
                    for (int q = 0; q < 8; ++q)
                        sv[q] = vsin(fmaf(pv, bases[q], off));
                    union { f16x8 v; f16x2 h[4]; } G;
                    #pragma unroll
                    for (int q = 0; q < 4; ++q)
                        G.h[q] = pk2(sv[2 * q], sv[2 * q + 1]);
                    U[u] = G.v;
                }
            }
            #pragma unroll
            for (int c = 0; c < 4; ++c) {
                f16x8 af = ((const f16x8*)WF)[(s * 4 + c) * 64 + lane];
                acc[0][c] = __builtin_amdgcn_mfma_f32_16x16x32_f16(af, U[0], acc[0][c], 0, 0, 0);
                acc[1][c] = __builtin_amdgcn_mfma_f32_16x16x32_f16(af, U[1], acc[1][c], 0, 0, 0);
            }
        }

        // ---- per tile: LN + GELU -> Pw, GEMM2, dense store ----------------
        #pragma unroll
        for (int u = 0; u < 2; ++u) {
            // LN stats (lane-local 16 + 2 shuffles)
            float s1 = 0.0f, s2 = 0.0f;
            #pragma unroll
            for (int c = 0; c < 4; ++c) {
                f32x4 b1q = *(const f32x4*)(b1 + 16 * c + 4 * g);
                #pragma unroll
                for (int r = 0; r < 4; ++r) {
                    float x = acc[u][c][r] + b1q[r];
                    acc[u][c][r] = x;
                    s1 += x; s2 += x * x;
                }
            }
            s1 += __shfl_xor(s1, 16); s2 += __shfl_xor(s2, 16);
            s1 += __shfl_xor(s1, 32); s2 += __shfl_xor(s2, 32);
            const float mu   = s1 * (1.0f / 64.0f);
            const float var  = s2 * (1.0f / 64.0f) - mu * mu;
            const float rstd = __builtin_amdgcn_rsqf(var + 1e-5f);

            // GELU via x*sigmoid(2u) (exact identity with tanh form) -> Pw
            #pragma unroll
            for (int c = 0; c < 4; ++c) {
                f32x4 gq = *(const f32x4*)(ln_g + 16 * c + 4 * g);
                f32x4 bq = *(const f32x4*)(ln_b + 16 * c + 4 * g);
                float gv[4];
                #pragma unroll
                for (int r = 0; r < 4; ++r) {
                    float x  = (acc[u][c][r] - mu) * rstd * gq[r] + bq[r];
                    float w  = x * (0.7978845608028654f + 0.0356774081363001f * x * x);
                    float e2 = __expf(w + w);
                    gv[r] = x * e2 * __builtin_amdgcn_rcpf(e2 + 1.0f);
                }
                union { f16x2 h[2]; uint2 u2; } W;
                W.h[0] = pk2(gv[0], gv[1]);
                W.h[1] = pk2(gv[2], gv[3]);
                *(uint2*)(Pw + n * 128 + (((unsigned)(32 * c + 8 * g)) ^ sw)) = W.u2;
            }

            // GEMM2: acc2[c] = O[ch 16c+4g+r][point n]
            f32x4 acc2[4];
            #pragma unroll
            for (int c = 0; c < 4; ++c) acc2[c] = (f32x4){0.0f, 0.0f, 0.0f, 0.0f};
            #pragma unroll
            for (int s = 0; s < 2; ++s) {
                f16x8 bf2 = *(const f16x8*)(Pw + n * 128 + (((unsigned)(64 * s + 16 * g)) ^ sw));
                #pragma unroll
                for (int c = 0; c < 4; ++c) {
                    f16x8 af = ((const f16x8*)WF)[(W1_FRAGS + s * 4 + c) * 64 + lane];
                    acc2[c] = __builtin_amdgcn_mfma_f32_16x16x32_f16(af, bf2, acc2[c], 0, 0, 0);
                }
            }

            if (use_feat) {
                // DENSE row write straight from registers: lane (g,n) owns
                // channels 16c+4g..16c+4g+3 of point (wbase + tile*16 + n).
                const int gs = wbase + (tp * 2 + u) * 16 + n;
                if (gs < NPTS) {
                    _Float16* dstp = featbuf + (size_t)gs * COUT + 4 * g;
                    #pragma unroll
                    for (int c = 0; c < 4; ++c) {
                        union { f16x2 h[2]; uint2 u2; } W;
                        W.h[0] = pk2(acc2[c][0], acc2[c][1]);
                        W.h[1] = pk2(acc2[c][2], acc2[c][3]);
                        *(uint2*)(dstp + 16 * c) = W.u2;
                    }
                }
            } else {
                // fallback: direct fp32 atomics (correctness path, not perf)
                const int st = wbase + (tp * 2 + u) * 16 + n;
                if (st < NPTS) {
                    const float pa1 = (a1 == 0) ? px[u] : ((a1 == 1) ? py[u] : pz[u]);
                    const float pa2 = (a2 == 0) ? px[u] : ((a2 == 1) ? py[u] : pz[u]);
                    const int cellr = cell_index(pa1) * GRID_W + cell_index(pa2);
                    #pragma unroll
                    for (int c = 0; c < 4; ++c)
                        #pragma unroll
                        for (int r = 0; r < 4; ++r)
                            unsafeAtomicAdd(&out[(size_t)(16 * c + 4 * g + r) * NCELL + cellr],
                                            acc2[c][r]);
                }
            }
        }
    }
}

// K4: per-cell reduce with VECTORIZED gather: lane loads uint4 (8 f16 ch),
// 8 lanes cover one 128B row, wave covers 8 rows per load instruction.
// 8 f32 acc per lane; 3 x shfl_xor final reduce. 1 cell/wave, 16 waves/block.
__global__ __launch_bounds__(1024)
void reduce_kernel(const _Float16* __restrict__ featbuf,
                   const int* __restrict__ sorted,
                   const unsigned int* __restrict__ starts,
                   const unsigned int* __restrict__ hist,
                   const float* __restrict__ b2,
                   float* __restrict__ out)
{
    __shared__ float R[16][66];
    const int lane  = threadIdx.x & 63;
    const int wv    = threadIdx.x >> 6;    // 0..15 = cell-within-block
    const int cbase = blockIdx.x * 16;
    const int cq    = lane & 7;            // channel octet: ch = cq*8 + j
    const int rsl   = lane >> 3;           // row slot 0..7

    const int cell = cbase + wv;
    const unsigned int s0  = starts[cell];
    const unsigned int cnt = hist[cell];

    float acc[8];
    #pragma unroll
    for (int j = 0; j < 8; ++j) acc[j] = 0.0f;

    for (unsigned int k = 0; k < cnt; k += 8) {
        const unsigned int kk = k + (unsigned int)rsl;
        const bool ok = kk < cnt;
        const int r = sorted[ok ? (s0 + kk) : s0];
        union { uint4 u; f16x2 h[4]; } V;
        V.u = *(const uint4*)(featbuf + (size_t)r * COUT + cq * 8);
        #pragma unroll
        for (int j = 0; j < 4; ++j) {
            acc[2 * j]     += ok ? (float)V.h[j].x : 0.0f;
            acc[2 * j + 1] += ok ? (float)V.h[j].y : 0.0f;
        }
    }
    #pragma unroll
    for (int m = 8; m <= 32; m <<= 1)
        #pragma unroll
        for (int j = 0; j < 8; ++j)
            acc[j] += __shfl_xor(acc[j], m);

    if (rsl == 0) {
        const float inv = 1.0f / fmaxf((float)cnt, 1.0f);
        float4 b2a = *(const float4*)(b2 + cq * 8);
        float4 b2b = *(const float4*)(b2 + cq * 8 + 4);
        const float bb[8] = {b2a.x, b2a.y, b2a.z, b2a.w, b2b.x, b2b.y, b2b.z, b2b.w};
        #pragma unroll
        for (int j = 0; j < 8; ++j)
            R[wv][cq * 8 + j] = cnt ? (acc[j] * inv + bb[j]) : 0.0f;
    }
    __syncthreads();

    // store: thread t -> out[ch = t>>4][cbase + (t&15)]; 64B contiguous per ch
    const int ch = threadIdx.x >> 4;
    const int ci = threadIdx.x & 15;
    out[ch * NCELL + cbase + ci] = R[ci][ch];
}

// K5 (fallback only): divide by counts + add b2 (guarded for empty cells)
__global__ void finalize_kernel(float* __restrict__ out,
                                const unsigned int* __restrict__ hist,
                                const float* __restrict__ b2)
{
    int t = blockIdx.x * 256 + threadIdx.x;
    int cell = t & (NCELL - 1);
    int ch   = t >> 16;
    float c  = (float)hist[cell];
    out[t] = out[t] / fmaxf(c, 1.0f) + ((c > 0.0f) ? b2[ch] : 0.0f);
}

extern "C" void kernel_launch(void* const* d_in, const int* in_sizes, int n_in,
                              void* d_out, int out_size, void* d_ws, size_t ws_size,
                              hipStream_t stream) {
    (void)in_sizes; (void)n_in; (void)out_size;
    const float* pos   = (const float*)d_in[0];
    const float* feats = (const float*)d_in[1];
    const float* W1    = (const float*)d_in[2];
    const float* b1    = (const float*)d_in[3];
    const float* ln_g  = (const float*)d_in[4];
    const float* ln_b  = (const float*)d_in[5];
    const float* W2    = (const float*)d_in[6];
    const float* b2    = (const float*)d_in[7];
    const int*   ax1   = (const int*)d_in[8];
    const int*   ax2   = (const int*)d_in[9];

    char* ws = (char*)d_ws;
    unsigned int* hist   = (unsigned int*)(ws + WS_HIST);
    unsigned int* starts = (unsigned int*)(ws + WS_STARTS);
    unsigned int* cr32   = (unsigned int*)(ws + WS_CR);
    int*          sorted = (int*)(ws + WS_SORT);
    _Float16*     wpk    = (_Float16*)(ws + WS_WPK);
    _Float16*     featbf = (_Float16*)(ws + WS_FEAT);

    float* out = (float*)d_out;
    const int use_feat = (ws_size >= WS_NEED) ? 1 : 0;

    hipMemsetAsync(hist, 0, NCELL * sizeof(unsigned int), stream);
    if (!use_feat)
        hipMemsetAsync(d_out, 0, (size_t)COUT * NCELL * sizeof(float), stream);

    pack_w_kernel<<<(W_HALFS + 255) / 256, 256, 0, stream>>>(W1, W2, wpk);
    mlp_mfma_kernel<<<MB_BLOCKS, 512, 0, stream>>>(
        pos, feats, wpk, b1, ln_g, ln_b, ax1, ax2, hist,
        use_feat ? cr32 : (unsigned int*)nullptr, featbf, out, use_feat);
    if (use_feat) {
        scan_fused_kernel<<<1, 1024, 0, stream>>>(hist, starts);
        build_sorted_kernel<<<PT_BLOCKS, 256, 0, stream>>>(cr32, starts, sorted);
        reduce_kernel<<<NCELL / 16, 1024, 0, stream>>>(featbf, sorted, starts, hist, b2, out);
    } else {
        finalize_kernel<<<(COUT * NCELL) / 256, 256, 0, stream>>>(out, hist, b2);
    }
}

// Round 7
// 224.361 us; speedup vs baseline: 1.0355x; 1.0021x over previous
//
#include <hip/hip_runtime.h>
#include <math.h>

// Problem constants (reference file)
#define NPTS   500000
#define CIN    16
#define COUT   64
#define GRID_W 256
#define NCELL  65536

// ws layout (bytes)
#define WS_HIST   0                      // 65536 u32  (256 KB)
#define WS_STARTS 262144                 // 65536 u32 segment starts (256 KB)
#define WS_CR     524288                 // 500000 u32 (cell | lrank<<16) (2 MB)
#define WS_SORT   2621440                // 500000 i32 sorted point ids (2 MB)
#define WS_WPK    4718592                // 18432 f16 frag-packed weights (36864 B)
#define WS_FEAT   4755456                // 500000*64 f16 feature rows (64 MB)
#define WS_NEED   (WS_FEAT + (size_t)NPTS * COUT * 2)

#define PT_BLOCKS ((NPTS + 255) / 256)   // 1954 (aux kernels, 256 thr)
#define MB_BLOCKS ((NPTS + 511) / 512)   // 977  (main kernel, 512 thr)

#define W_HALFS   18432                  // (28+8) frags * 64 lanes * 8 halfs
#define W1_FRAGS  28                     // 7 k-steps * 4 ch-tiles

typedef _Float16 f16x8 __attribute__((ext_vector_type(8)));
typedef _Float16 f16x2 __attribute__((ext_vector_type(2)));
typedef float    f32x4 __attribute__((ext_vector_type(4)));

__device__ __forceinline__ f16x2 pk2(float a, float b) {
    auto r = __builtin_amdgcn_cvt_pkrtz(a, b);   // v_cvt_pkrtz_f16_f32
    union { decltype(r) x; f16x2 y; } u; u.x = r;
    return u.y;
}

// raw v_sin_f32: input in REVOLUTIONS (|x| < 1 here, no range reduction needed)
__device__ __forceinline__ float vsin(float x) {
    float r;
    asm("v_sin_f32 %0, %1" : "=v"(r) : "v"(x));
    return r;
}

__device__ __forceinline__ int cell_index(float v) {
    float nf = fminf(fmaxf((v + 1.0f) * 0.5f, 0.0f), 1.0f);
    int i = (int)floorf(nf * 256.0f);
    return i > 255 ? 255 : i;
}

__device__ __forceinline__ int flat_of(const float* pos, int p, int a1, int a2) {
    float pa1 = pos[p * 3 + a1];
    float pa2 = pos[p * 3 + a2];
    return cell_index(pa1) * GRID_W + cell_index(pa2);
}

// K0: fused weight-pack (frag order) + histogram + (cell,lrank) ids.
// pos reads are LDS-staged: block loads 3 KB contiguously via float4, each
// thread then reads its 3 floats from LDS (gcd(3,32)=1 -> conflict-free).
__global__ __launch_bounds__(256)
void pack_hist_kernel(const float* __restrict__ W1,
                      const float* __restrict__ W2,
                      const float* __restrict__ pos,
                      const int* __restrict__ ax1p,
                      const int* __restrict__ ax2p,
                      _Float16* __restrict__ wpk,
                      unsigned int* __restrict__ hist,
                      unsigned int* __restrict__ cr32)
{
    __shared__ float PSH[768];
    const int t = threadIdx.x;
    const int i = blockIdx.x * 256 + t;

    if (i < W_HALFS) {
        int j = i & 7, lane = (i >> 3) & 63, f = i >> 9;
        int k  = ((f < W1_FRAGS) ? (f >> 2) : ((f - W1_FRAGS) >> 2)) * 32 + ((lane >> 4) << 3) + j;
        int ch = (f & 3) * 16 + (lane & 15);
        float v;
        if (f < W1_FRAGS) v = (k < 208) ? W1[k * 64 + ch] : 0.0f;
        else              v = W2[k * 64 + ch];
        wpk[i] = (_Float16)v;
    }

    // stage this block's 256 points (768 floats, 3072 B) into LDS
    const int fbase = blockIdx.x * 768;
    if (fbase + 768 <= NPTS * 3) {
        if (t < 192)
            ((float4*)PSH)[t] = ((const float4*)(pos + fbase))[t];
    } else {
        const int nf = NPTS * 3 - fbase;
        for (int j = t; j < nf; j += 256) PSH[j] = pos[fbase + j];
    }
    __syncthreads();

    if (i < NPTS) {
        const int a1 = ax1p[0], a2 = ax2p[0];
        const float pa1 = PSH[3 * t + a1];
        const float pa2 = PSH[3 * t + a2];
        const int flat = cell_index(pa1) * GRID_W + cell_index(pa2);
        const unsigned int old = atomicAdd(&hist[flat], 1u);
        if (cr32) cr32[i] = (unsigned int)flat | (old << 16);
    }
}

// K1: single-block exclusive scan of hist -> starts (64 cells per thread).
__global__ __launch_bounds__(1024)
void scan_fused_kernel(const unsigned int* __restrict__ hist,
                       unsigned int* __restrict__ starts)
{
    __shared__ unsigned int ssum[1024];
    const int t = threadIdx.x;
    const int base = t * 64;
    unsigned int s = 0;
    #pragma unroll
    for (int i = 0; i < 64; i += 4) {
        uint4 q = *(const uint4*)(hist + base + i);
        s += q.x + q.y + q.z + q.w;
    }
    ssum[t] = s;
    __syncthreads();
    for (int off = 1; off < 1024; off <<= 1) {
        unsigned int add = (t >= off) ? ssum[t - off] : 0u;
        __syncthreads();
        ssum[t] += add;
        __syncthreads();
    }
    unsigned int run = ssum[t] - s;   // exclusive prefix of this chunk
    #pragma unroll
    for (int i = 0; i < 64; i += 4) {
        uint4 q = *(const uint4*)(hist + base + i);
        starts[base + i + 0] = run; run += q.x;
        starts[base + i + 1] = run; run += q.y;
        starts[base + i + 2] = run; run += q.z;
        starts[base + i + 3] = run; run += q.w;
    }
}

// K2: sorted[starts[cell]+lrank] = p. Scattered 4B writes into a 2 MB target
// -> fully L2-absorbed (the cheap kind of scatter).
__global__ void build_sorted_kernel(const unsigned int* __restrict__ cr32,
                                    const unsigned int* __restrict__ starts,
                                    int* __restrict__ sorted)
{
    int p = blockIdx.x * 256 + threadIdx.x;
    if (p >= NPTS) return;
    unsigned int cr = cr32[p];
    sorted[starts[cr & 0xFFFFu] + (cr >> 16)] = p;
}

// K3: MFMA MLP (round-5 body, measured 56.5 us), swapped operands
// (weights = A-frag, generated X^T = B-frag). D is channel-major: lane (g,n)
// holds channels {16c+4g+r} of point n. Epilogue: DENSE register->global row
// writes to featbuf[point]; rank indirection lives in the reduce's gather.
__global__ __launch_bounds__(512, 4)
void mlp_mfma_kernel(const float* __restrict__ pos,
                     const float* __restrict__ feats,
                     const _Float16* __restrict__ wpk,
                     const float* __restrict__ b1,
                     const float* __restrict__ ln_g,
                     const float* __restrict__ ln_b,
                     const int*   __restrict__ ax1p,
                     const int*   __restrict__ ax2p,
                     _Float16* __restrict__ featbuf,
                     float* __restrict__ out,
                     int use_feat)
{
    __shared__ __align__(16) _Float16 WF[W_HALFS];   // 36864 B
    __shared__ __align__(16) _Float16 PS[8 * 1024];  // 16384 B (2 KB per wave)

    // stage frag-packed weights (coalesced 16B copies)
    {
        const uint4* src = (const uint4*)wpk;
        uint4* dst = (uint4*)WF;
        for (int i = threadIdx.x; i < W_HALFS / 8; i += 512) dst[i] = src[i];
    }

    const int lane = threadIdx.x & 63;
    const int wv   = threadIdx.x >> 6;
    const int g    = lane >> 4;        // quad
    const int n    = lane & 15;        // point-within-tile (B-col / D-col)
    char* Pw = (char*)(PS + wv * 1024);            // 2048 B per wave
    const unsigned sw = (unsigned)((n & 7) << 4);  // XOR swizzle (byte, 16B unit)

    const int wbase = blockIdx.x * 512 + wv * 64;

    // lane-constant PE base frequency IN REVOLUTIONS: 0.25 * 2^(f0/32)
    const float base  = 0.25f * exp2f((float)((8 * g + 16) & 31) * 0.03125f);
    const float RSTEP = 1.02189714865411668f;    // 2^(1/32)

    __syncthreads();   // WF visible

    #pragma unroll 1
    for (int tp = 0; tp < 2; ++tp) {
        // ---- load 2 tiles' point data -------------------------------------
        float px[2], py[2], pz[2];
        f16x8 fH[2];
        #pragma unroll
        for (int u = 0; u < 2; ++u) {
            const int st = wbase + (tp * 2 + u) * 16 + n;
            const int p  = (st < NPTS) ? st : 0;
            px[u] = pos[3 * p + 0];
            py[u] = pos[3 * p + 1];
            pz[u] = pos[3 * p + 2];
            if (g < 2) {
                const float4* fr = (const float4*)(feats + (size_t)p * CIN + g * 8);
                float4 fa = fr[0], fb = fr[1];
                union { f16x8 v; f16x2 h[4]; } Uf;
                Uf.h[0] = pk2(fa.x, fa.y); Uf.h[1] = pk2(fa.z, fa.w);
                Uf.h[2] = pk2(fb.x, fb.y); Uf.h[3] = pk2(fb.z, fb.w);
                fH[u] = Uf.v;
            }
        }

        // ---- GEMM1: acc[u][c] = H[ch 16c+4g+r][point n], K = 224 ----------
        f32x4 acc[2][4];
        #pragma unroll
        for (int u = 0; u < 2; ++u)
            #pragma unroll
            for (int c = 0; c < 4; ++c)
                acc[u][c] = (f32x4){0.0f, 0.0f, 0.0f, 0.0f};

        #pragma unroll
        for (int s = 0; s < 7; ++s) {
            f16x8 U[2];
            const int k0 = s * 32 + g * 8;
            if (s == 0 && g < 2) {               // feats (pre-packed)
                U[0] = fH[0]; U[1] = fH[1];
            } else if (k0 >= 208) {              // zero pad (s==6, g>=2)
                union { f16x8 v; f16x2 h[4]; } Z;
                #pragma unroll
                for (int q = 0; q < 4; ++q) Z.h[q] = pk2(0.0f, 0.0f);
                U[0] = Z.v; U[1] = Z.v;
            } else {                             // PE: v_sin in revolutions
                const int   e    = k0 - 16;
                const float off  = (e & 32) ? 0.25f : 0.0f;
                const float offc = (e & 32) ? (0.25f * (1.0f - RSTEP)) : 0.0f;
                #pragma unroll
                for (int u = 0; u < 2; ++u) {
                    const float pv = (e < 64) ? px[u] : ((e < 128) ? py[u] : pz[u]);
                    float a = fmaf(pv, base, off);
                    union { f16x8 v; f16x2 h[4]; } G;
                    #pragma unroll
                    for (int q = 0; q < 4; ++q) {
                        float v0 = vsin(a); a = fmaf(a, RSTEP, offc);
                        float v1 = vsin(a); a = fmaf(a, RSTEP, offc);
                        G.h[q] = pk2(v0, v1);
                    }
                    U[u] = G.v;
                }
            }
            #pragma unroll
            for (int c = 0; c < 4; ++c) {
                f16x8 af = ((const f16x8*)WF)[(s * 4 + c) * 64 + lane];
                acc[0][c] = __builtin_amdgcn_mfma_f32_16x16x32_f16(af, U[0], acc[0][c], 0, 0, 0);
                acc[1][c] = __builtin_amdgcn_mfma_f32_16x16x32_f16(af, U[1], acc[1][c], 0, 0, 0);
            }
        }

        // ---- per tile: LN + GELU -> Pw, GEMM2, dense store ----------------
        #pragma unroll
        for (int u = 0; u < 2; ++u) {
            // LN stats (lane-local 16 + 2 shuffles)
            float s1 = 0.0f, s2 = 0.0f;
            #pragma unroll
            for (int c = 0; c < 4; ++c) {
                f32x4 b1q = *(const f32x4*)(b1 + 16 * c + 4 * g);
                #pragma unroll
                for (int r = 0; r < 4; ++r) {
                    float x = acc[u][c][r] + b1q[r];
                    acc[u][c][r] = x;
                    s1 += x; s2 += x * x;
                }
            }
            s1 += __shfl_xor(s1, 16); s2 += __shfl_xor(s2, 16);
            s1 += __shfl_xor(s1, 32); s2 += __shfl_xor(s2, 32);
            const float mu   = s1 * (1.0f / 64.0f);
            const float var  = s2 * (1.0f / 64.0f) - mu * mu;
            const float rstd = __builtin_amdgcn_rsqf(var + 1e-5f);

            // GELU via x*sigmoid(2u) (exact identity with tanh form) -> Pw
            #pragma unroll
            for (int c = 0; c < 4; ++c) {
                f32x4 gq = *(const f32x4*)(ln_g + 16 * c + 4 * g);
                f32x4 bq = *(const f32x4*)(ln_b + 16 * c + 4 * g);
                float gv[4];
                #pragma unroll
                for (int r = 0; r < 4; ++r) {
                    float x  = (acc[u][c][r] - mu) * rstd * gq[r] + bq[r];
                    float w  = x * (0.7978845608028654f + 0.0356774081363001f * x * x);
                    float e2 = __expf(w + w);
                    gv[r] = x * e2 * __builtin_amdgcn_rcpf(e2 + 1.0f);
                }
                union { f16x2 h[2]; uint2 u2; } W;
                W.h[0] = pk2(gv[0], gv[1]);
                W.h[1] = pk2(gv[2], gv[3]);
                *(uint2*)(Pw + n * 128 + (((unsigned)(32 * c + 8 * g)) ^ sw)) = W.u2;
            }

            // GEMM2: acc2[c] = O[ch 16c+4g+r][point n]
            f32x4 acc2[4];
            #pragma unroll
            for (int c = 0; c < 4; ++c) acc2[c] = (f32x4){0.0f, 0.0f, 0.0f, 0.0f};
            #pragma unroll
            for (int s = 0; s < 2; ++s) {
                f16x8 bf2 = *(const f16x8*)(Pw + n * 128 + (((unsigned)(64 * s + 16 * g)) ^ sw));
                #pragma unroll
                for (int c = 0; c < 4; ++c) {
                    f16x8 af = ((const f16x8*)WF)[(W1_FRAGS + s * 4 + c) * 64 + lane];
                    acc2[c] = __builtin_amdgcn_mfma_f32_16x16x32_f16(af, bf2, acc2[c], 0, 0, 0);
                }
            }

            if (use_feat) {
                // DENSE row write straight from registers: lane (g,n) owns
                // channels 16c+4g..16c+4g+3 of point (wbase + tile*16 + n).
                const int gs = wbase + (tp * 2 + u) * 16 + n;
                if (gs < NPTS) {
                    _Float16* dstp = featbuf + (size_t)gs * COUT + 4 * g;
                    #pragma unroll
                    for (int c = 0; c < 4; ++c) {
                        union { f16x2 h[2]; uint2 u2; } W;
                        W.h[0] = pk2(acc2[c][0], acc2[c][1]);
                        W.h[1] = pk2(acc2[c][2], acc2[c][3]);
                        *(uint2*)(dstp + 16 * c) = W.u2;
                    }
                }
            } else {
                // fallback: direct fp32 atomics (correctness path, not perf)
                const int st = wbase + (tp * 2 + u) * 16 + n;
                if (st < NPTS) {
                    const int cellr = flat_of(pos, st, ax1p[0], ax2p[0]);
                    #pragma unroll
                    for (int c = 0; c < 4; ++c)
                        #pragma unroll
                        for (int r = 0; r < 4; ++r)
                            unsafeAtomicAdd(&out[(size_t)(16 * c + 4 * g + r) * NCELL + cellr],
                                            acc2[c][r]);
                }
            }
        }
    }
}

// K4: per-cell reduce with VECTORIZED gather: lane loads uint4 (8 f16 ch),
// 8 lanes cover one 128B row, wave covers 8 rows per load instruction.
// 8 f32 acc per lane; 3 x shfl_xor final reduce. 1 cell/wave, 16 waves/block.
__global__ __launch_bounds__(1024)
void reduce_kernel(const _Float16* __restrict__ featbuf,
                   const int* __restrict__ sorted,
                   const unsigned int* __restrict__ starts,
                   const unsigned int* __restrict__ hist,
                   const float* __restrict__ b2,
                   float* __restrict__ out)
{
    __shared__ float R[16][66];
    const int lane  = threadIdx.x & 63;
    const int wv    = threadIdx.x >> 6;    // 0..15 = cell-within-block
    const int cbase = blockIdx.x * 16;
    const int cq    = lane & 7;            // channel octet: ch = cq*8 + j
    const int rsl   = lane >> 3;           // row slot 0..7

    const int cell = cbase + wv;
    const unsigned int s0  = starts[cell];
    const unsigned int cnt = hist[cell];

    float acc[8];
    #pragma unroll
    for (int j = 0; j < 8; ++j) acc[j] = 0.0f;

    for (unsigned int k = 0; k < cnt; k += 8) {
        const unsigned int kk = k + (unsigned int)rsl;
        const bool ok = kk < cnt;
        const int r = sorted[ok ? (s0 + kk) : s0];
        union { uint4 u; f16x2 h[4]; } V;
        V.u = *(const uint4*)(featbuf + (size_t)r * COUT + cq * 8);
        #pragma unroll
        for (int j = 0; j < 4; ++j) {
            acc[2 * j]     += ok ? (float)V.h[j].x : 0.0f;
            acc[2 * j + 1] += ok ? (float)V.h[j].y : 0.0f;
        }
    }
    #pragma unroll
    for (int m = 8; m <= 32; m <<= 1)
        #pragma unroll
        for (int j = 0; j < 8; ++j)
            acc[j] += __shfl_xor(acc[j], m);

    if (rsl == 0) {
        const float inv = 1.0f / fmaxf((float)cnt, 1.0f);
        float4 b2a = *(const float4*)(b2 + cq * 8);
        float4 b2b = *(const float4*)(b2 + cq * 8 + 4);
        const float bb[8] = {b2a.x, b2a.y, b2a.z, b2a.w, b2b.x, b2b.y, b2b.z, b2b.w};
        #pragma unroll
        for (int j = 0; j < 8; ++j)
            R[wv][cq * 8 + j] = cnt ? (acc[j] * inv + bb[j]) : 0.0f;
    }
    __syncthreads();

    // store: thread t -> out[ch = t>>4][cbase + (t&15)]; 64B contiguous per ch
    const int ch = threadIdx.x >> 4;
    const int ci = threadIdx.x & 15;
    out[ch * NCELL + cbase + ci] = R[ci][ch];
}

// K5 (fallback only): divide by counts + add b2 (guarded for empty cells)
__global__ void finalize_kernel(float* __restrict__ out,
                                const unsigned int* __restrict__ hist,
                                const float* __restrict__ b2)
{
    int t = blockIdx.x * 256 + threadIdx.x;
    int cell = t & (NCELL - 1);
    int ch   = t >> 16;
    float c  = (float)hist[cell];
    out[t] = out[t] / fmaxf(c, 1.0f) + ((c > 0.0f) ? b2[ch] : 0.0f);
}

extern "C" void kernel_launch(void* const* d_in, const int* in_sizes, int n_in,
                              void* d_out, int out_size, void* d_ws, size_t ws_size,
                              hipStream_t stream) {
    (void)in_sizes; (void)n_in; (void)out_size;
    const float* pos   = (const float*)d_in[0];
    const float* feats = (const float*)d_in[1];
    const float* W1    = (const float*)d_in[2];
    const float* b1    = (const float*)d_in[3];
    const float* ln_g  = (const float*)d_in[4];
    const float* ln_b  = (const float*)d_in[5];
    const float* W2    = (const float*)d_in[6];
    const float* b2    = (const float*)d_in[7];
    const int*   ax1   = (const int*)d_in[8];
    const int*   ax2   = (const int*)d_in[9];

    char* ws = (char*)d_ws;
    unsigned int* hist   = (unsigned int*)(ws + WS_HIST);
    unsigned int* starts = (unsigned int*)(ws + WS_STARTS);
    unsigned int* cr32   = (unsigned int*)(ws + WS_CR);
    int*          sorted = (int*)(ws + WS_SORT);
    _Float16*     wpk    = (_Float16*)(ws + WS_WPK);
    _Float16*     featbf = (_Float16*)(ws + WS_FEAT);

    float* out = (float*)d_out;
    const int use_feat = (ws_size >= WS_NEED) ? 1 : 0;

    hipMemsetAsync(hist, 0, NCELL * sizeof(unsigned int), stream);
    if (!use_feat)
        hipMemsetAsync(d_out, 0, (size_t)COUT * NCELL * sizeof(float), stream);

    pack_hist_kernel<<<PT_BLOCKS, 256, 0, stream>>>(
        W1, W2, pos, ax1, ax2, wpk, hist,
        use_feat ? cr32 : (unsigned int*)nullptr);
    if (use_feat) {
        scan_fused_kernel<<<1, 1024, 0, stream>>>(hist, starts);
        build_sorted_kernel<<<PT_BLOCKS, 256, 0, stream>>>(cr32, starts, sorted);
    }
    mlp_mfma_kernel<<<MB_BLOCKS, 512, 0, stream>>>(
        pos, feats, wpk, b1, ln_g, ln_b, ax1, ax2, featbf, out, use_feat);
    if (use_feat)
        reduce_kernel<<<NCELL / 16, 1024, 0, stream>>>(featbf, sorted, starts, hist, b2, out);
    else
        finalize_kernel<<<(COUT * NCELL) / 256, 256, 0, stream>>>(out, hist, b2);
}

// Round 9
// 218.575 us; speedup vs baseline: 1.0629x; 1.0265x over previous
//
#include <hip/hip_runtime.h>
#include <math.h>

// Problem constants (reference file)
#define NPTS   500000
#define CIN    16
#define COUT   64
#define GRID_W 256
#define NCELL  65536

// ws layout (bytes)
#define WS_HIST   0                      // 65536 u32  (256 KB)
#define WS_STARTS 262144                 // 65536 u32 segment starts (256 KB)
#define WS_CR     524288                 // 500000 u32 (cell | lrank<<16) (2 MB)
#define WS_SORT   2621440                // 500000 i32 sorted point ids (2 MB)
#define WS_WPK    4718592                // 18432 f16 frag-packed weights (36864 B)
#define WS_FEAT   4755456                // 500000*64 f16 feature rows (64 MB)
#define WS_NEED   (WS_FEAT + (size_t)NPTS * COUT * 2)

#define PT_BLOCKS ((NPTS + 255) / 256)   // 1954 (aux kernels, 256 thr)
#define MB_BLOCKS ((NPTS + 511) / 512)   // 977  (main kernel, 512 thr)

#define W_HALFS   18432                  // (28+8) frags * 64 lanes * 8 halfs
#define W1_FRAGS  28                     // 7 k-steps * 4 ch-tiles

typedef _Float16 f16x8 __attribute__((ext_vector_type(8)));
typedef _Float16 f16x2 __attribute__((ext_vector_type(2)));
typedef float    f32x4 __attribute__((ext_vector_type(4)));

__device__ __forceinline__ f16x2 pk2(float a, float b) {
    auto r = __builtin_amdgcn_cvt_pkrtz(a, b);   // v_cvt_pkrtz_f16_f32
    union { decltype(r) x; f16x2 y; } u; u.x = r;
    return u.y;
}

// raw v_sin_f32: input in REVOLUTIONS (|x| < 1 here, no range reduction needed)
__device__ __forceinline__ float vsin(float x) {
    float r;
    asm("v_sin_f32 %0, %1" : "=v"(r) : "v"(x));
    return r;
}

__device__ __forceinline__ int cell_index(float v) {
    float nf = fminf(fmaxf((v + 1.0f) * 0.5f, 0.0f), 1.0f);
    int i = (int)floorf(nf * 256.0f);
    return i > 255 ? 255 : i;
}

__device__ __forceinline__ int flat_of(const float* pos, int p, int a1, int a2) {
    float pa1 = pos[p * 3 + a1];
    float pa2 = pos[p * 3 + a2];
    return cell_index(pa1) * GRID_W + cell_index(pa2);
}

// K0: tiny weight-pack (frag order) — histogram lives in the MLP epilogue now.
__global__ void pack_w_kernel(const float* __restrict__ W1,
                              const float* __restrict__ W2,
                              _Float16* __restrict__ wpk)
{
    int i = blockIdx.x * 256 + threadIdx.x;
    if (i >= W_HALFS) return;
    int j = i & 7, lane = (i >> 3) & 63, f = i >> 9;
    int k  = ((f < W1_FRAGS) ? (f >> 2) : ((f - W1_FRAGS) >> 2)) * 32 + ((lane >> 4) << 3) + j;
    int ch = (f & 3) * 16 + (lane & 15);
    float v;
    if (f < W1_FRAGS) v = (k < 208) ? W1[k * 64 + ch] : 0.0f;
    else              v = W2[k * 64 + ch];
    wpk[i] = (_Float16)v;
}

// K1: single-block exclusive scan of hist -> starts (64 cells per thread).
__global__ __launch_bounds__(1024)
void scan_fused_kernel(const unsigned int* __restrict__ hist,
                       unsigned int* __restrict__ starts)
{
    __shared__ unsigned int ssum[1024];
    const int t = threadIdx.x;
    const int base = t * 64;
    unsigned int s = 0;
    #pragma unroll
    for (int i = 0; i < 64; i += 4) {
        uint4 q = *(const uint4*)(hist + base + i);
        s += q.x + q.y + q.z + q.w;
    }
    ssum[t] = s;
    __syncthreads();
    for (int off = 1; off < 1024; off <<= 1) {
        unsigned int add = (t >= off) ? ssum[t - off] : 0u;
        __syncthreads();
        ssum[t] += add;
        __syncthreads();
    }
    unsigned int run = ssum[t] - s;   // exclusive prefix of this chunk
    #pragma unroll
    for (int i = 0; i < 64; i += 4) {
        uint4 q = *(const uint4*)(hist + base + i);
        starts[base + i + 0] = run; run += q.x;
        starts[base + i + 1] = run; run += q.y;
        starts[base + i + 2] = run; run += q.z;
        starts[base + i + 3] = run; run += q.w;
    }
}

// K2: sorted[starts[cell]+lrank] = p. Scattered 4B writes into a 2 MB target
// -> fully L2-absorbed (the cheap kind of scatter).
__global__ void build_sorted_kernel(const unsigned int* __restrict__ cr32,
                                    const unsigned int* __restrict__ starts,
                                    int* __restrict__ sorted)
{
    int p = blockIdx.x * 256 + threadIdx.x;
    if (p >= NPTS) return;
    unsigned int cr = cr32[p];
    sorted[starts[cr & 0xFFFFu] + (cr >> 16)] = p;
}

// K3: MFMA MLP (round-5 body, measured 56.5 us) + rank assignment in the
// EPILOGUE: the returning atomicAdd is issued after the wave's featbuf store,
// so its ~700cy round trip overlaps other waves' MFMA (R6 put it at the HEAD
// and every wave stalled before its own compute: +30us — placement matters).
__global__ __launch_bounds__(512, 4)
void mlp_mfma_kernel(const float* __restrict__ pos,
                     const float* __restrict__ feats,
                     const _Float16* __restrict__ wpk,
                     const float* __restrict__ b1,
                     const float* __restrict__ ln_g,
                     const float* __restrict__ ln_b,
                     const int*   __restrict__ ax1p,
                     const int*   __restrict__ ax2p,
                     unsigned int* __restrict__ hist,
                     unsigned int* __restrict__ cr32,
                     _Float16* __restrict__ featbuf,
                     float* __restrict__ out,
                     int use_feat)
{
    __shared__ __align__(16) _Float16 WF[W_HALFS];   // 36864 B
    __shared__ __align__(16) _Float16 PS[8 * 1024];  // 16384 B (2 KB per wave)

    // stage frag-packed weights (coalesced 16B copies)
    {
        const uint4* src = (const uint4*)wpk;
        uint4* dst = (uint4*)WF;
        for (int i = threadIdx.x; i < W_HALFS / 8; i += 512) dst[i] = src[i];
    }

    const int lane = threadIdx.x & 63;
    const int wv   = threadIdx.x >> 6;
    const int g    = lane >> 4;        // quad
    const int n    = lane & 15;        // point-within-tile (B-col / D-col)
    char* Pw = (char*)(PS + wv * 1024);            // 2048 B per wave
    const unsigned sw = (unsigned)((n & 7) << 4);  // XOR swizzle (byte, 16B unit)

    const int wbase = blockIdx.x * 512 + wv * 64;
    const int a1 = ax1p[0], a2 = ax2p[0];

    // lane-constant PE base frequency IN REVOLUTIONS: 0.25 * 2^(f0/32)
    const float base  = 0.25f * exp2f((float)((8 * g + 16) & 31) * 0.03125f);
    const float RSTEP = 1.02189714865411668f;    // 2^(1/32)

    __syncthreads();   // WF visible

    #pragma unroll 1
    for (int tp = 0; tp < 2; ++tp) {
        // ---- load 2 tiles' point data -------------------------------------
        float px[2], py[2], pz[2];
        f16x8 fH[2];
        #pragma unroll
        for (int u = 0; u < 2; ++u) {
            const int st = wbase + (tp * 2 + u) * 16 + n;
            const int p  = (st < NPTS) ? st : 0;
            px[u] = pos[3 * p + 0];
            py[u] = pos[3 * p + 1];
            pz[u] = pos[3 * p + 2];
            if (g < 2) {
                const float4* fr = (const float4*)(feats + (size_t)p * CIN + g * 8);
                float4 fa = fr[0], fb = fr[1];
                union { f16x8 v; f16x2 h[4]; } Uf;
                Uf.h[0] = pk2(fa.x, fa.y); Uf.h[1] = pk2(fa.z, fa.w);
                Uf.h[2] = pk2(fb.x, fb.y); Uf.h[3] = pk2(fb.z, fb.w);
                fH[u] = Uf.v;
            }
        }

        // ---- GEMM1: acc[u][c] = H[ch 16c+4g+r][point n], K = 224 ----------
        f32x4 acc[2][4];
        #pragma unroll
        for (int u = 0; u < 2; ++u)
            #pragma unroll
            for (int c = 0; c < 4; ++c)
                acc[u][c] = (f32x4){0.0f, 0.0f, 0.0f, 0.0f};

        #pragma unroll
        for (int s = 0; s < 7; ++s) {
            f16x8 U[2];
            const int k0 = s * 32 + g * 8;
            if (s == 0 && g < 2) {               // feats (pre-packed)
                U[0] = fH[0]; U[1] = fH[1];
            } else if (k0 >= 208) {              // zero pad (s==6, g>=2)
                union { f16x8 v; f16x2 h[4]; } Z;
                #pragma unroll
                for (int q = 0; q < 4; ++q) Z.h[q] = pk2(0.0f, 0.0f);
                U[0] = Z.v; U[1] = Z.v;
            } else {                             // PE: v_sin in revolutions
                const int   e    = k0 - 16;
                const float off  = (e & 32) ? 0.25f : 0.0f;
                const float offc = (e & 32) ? (0.25f * (1.0f - RSTEP)) : 0.0f;
                #pragma unroll
                for (int u = 0; u < 2; ++u) {
                    const float pv = (e < 64) ? px[u] : ((e < 128) ? py[u] : pz[u]);
                    float a = fmaf(pv, base, off);
                    union { f16x8 v; f16x2 h[4]; } G;
                    #pragma unroll
                    for (int q = 0; q < 4; ++q) {
                        float v0 = vsin(a); a = fmaf(a, RSTEP, offc);
                        float v1 = vsin(a); a = fmaf(a, RSTEP, offc);
                        G.h[q] = pk2(v0, v1);
                    }
                    U[u] = G.v;
                }
            }
            #pragma unroll
            for (int c = 0; c < 4; ++c) {
                f16x8 af = ((const f16x8*)WF)[(s * 4 + c) * 64 + lane];
                acc[0][c] = __builtin_amdgcn_mfma_f32_16x16x32_f16(af, U[0], acc[0][c], 0, 0, 0);
                acc[1][c] = __builtin_amdgcn_mfma_f32_16x16x32_f16(af, U[1], acc[1][c], 0, 0, 0);
            }
        }

        // ---- per tile: LN + GELU -> Pw, GEMM2, dense store ----------------
        #pragma unroll
        for (int u = 0; u < 2; ++u) {
            // LN stats (lane-local 16 + 2 shuffles)
            float s1 = 0.0f, s2 = 0.0f;
            #pragma unroll
            for (int c = 0; c < 4; ++c) {
                f32x4 b1q = *(const f32x4*)(b1 + 16 * c + 4 * g);
                #pragma unroll
                for (int r = 0; r < 4; ++r) {
                    float x = acc[u][c][r] + b1q[r];
                    acc[u][c][r] = x;
                    s1 += x; s2 += x * x;
                }
            }
            s1 += __shfl_xor(s1, 16); s2 += __shfl_xor(s2, 16);
            s1 += __shfl_xor(s1, 32); s2 += __shfl_xor(s2, 32);
            const float mu   = s1 * (1.0f / 64.0f);
            const float var  = s2 * (1.0f / 64.0f) - mu * mu;
            const float rstd = __builtin_amdgcn_rsqf(var + 1e-5f);

            // GELU via x*sigmoid(2u) (exact identity with tanh form) -> Pw
            #pragma unroll
            for (int c = 0; c < 4; ++c) {
                f32x4 gq = *(const f32x4*)(ln_g + 16 * c + 4 * g);
                f32x4 bq = *(const f32x4*)(ln_b + 16 * c + 4 * g);
                float gv[4];
                #pragma unroll
                for (int r = 0; r < 4; ++r) {
                    float x  = (acc[u][c][r] - mu) * rstd * gq[r] + bq[r];
                    float w  = x * (0.7978845608028654f + 0.0356774081363001f * x * x);
                    float e2 = __expf(w + w);
                    gv[r] = x * e2 * __builtin_amdgcn_rcpf(e2 + 1.0f);
                }
                union { f16x2 h[2]; uint2 u2; } W;
                W.h[0] = pk2(gv[0], gv[1]);
                W.h[1] = pk2(gv[2], gv[3]);
                *(uint2*)(Pw + n * 128 + (((unsigned)(32 * c + 8 * g)) ^ sw)) = W.u2;
            }

            // GEMM2: acc2[c] = O[ch 16c+4g+r][point n]
            f32x4 acc2[4];
            #pragma unroll
            for (int c = 0; c < 4; ++c) acc2[c] = (f32x4){0.0f, 0.0f, 0.0f, 0.0f};
            #pragma unroll
            for (int s = 0; s < 2; ++s) {
                f16x8 bf2 = *(const f16x8*)(Pw + n * 128 + (((unsigned)(64 * s + 16 * g)) ^ sw));
                #pragma unroll
                for (int c = 0; c < 4; ++c) {
                    f16x8 af = ((const f16x8*)WF)[(W1_FRAGS + s * 4 + c) * 64 + lane];
                    acc2[c] = __builtin_amdgcn_mfma_f32_16x16x32_f16(af, bf2, acc2[c], 0, 0, 0);
                }
            }

            if (use_feat) {
                // DENSE row write straight from registers: lane (g,n) owns
                // channels 16c+4g..16c+4g+3 of point (wbase + tile*16 + n).
                const int gs = wbase + (tp * 2 + u) * 16 + n;
                if (gs < NPTS) {
                    _Float16* dstp = featbuf + (size_t)gs * COUT + 4 * g;
                    #pragma unroll
                    for (int c = 0; c < 4; ++c) {
                        union { f16x2 h[2]; uint2 u2; } W;
                        W.h[0] = pk2(acc2[c][0], acc2[c][1]);
                        W.h[1] = pk2(acc2[c][2], acc2[c][3]);
                        *(uint2*)(dstp + 16 * c) = W.u2;
                    }
                }
            } else {
                // fallback: direct fp32 atomics (correctness path, not perf)
                const int st = wbase + (tp * 2 + u) * 16 + n;
                if (st < NPTS) {
                    const int cellr = flat_of(pos, st, ax1p[0], ax2p[0]);
                    #pragma unroll
                    for (int c = 0; c < 4; ++c)
                        #pragma unroll
                        for (int r = 0; r < 4; ++r)
                            unsafeAtomicAdd(&out[(size_t)(16 * c + 4 * g + r) * NCELL + cellr],
                                            acc2[c][r]);
                }
            }
        }

        // ---- rank assignment (epilogue placement: latency hides under other
        // waves' MFMA; tp=0's atomics additionally hide under tp=1's GEMM).
        // Lane group g==0 handles tile u=0, g==1 handles u=1 (pos in regs).
        {
            const int st2 = wbase + (tp * 2 + (g & 1)) * 16 + n;
            if (g < 2 && st2 < NPTS) {
                const float qx = (g & 1) ? px[1] : px[0];
                const float qy = (g & 1) ? py[1] : py[0];
                const float qz = (g & 1) ? pz[1] : pz[0];
                const float pa1 = (a1 == 0) ? qx : ((a1 == 1) ? qy : qz);
                const float pa2 = (a2 == 0) ? qx : ((a2 == 1) ? qy : qz);
                const int flat = cell_index(pa1) * GRID_W + cell_index(pa2);
                const unsigned int old = atomicAdd(&hist[flat], 1u);
                if (cr32) cr32[st2] = (unsigned int)flat | (old << 16);
            }
        }
    }
}

// K4: per-cell reduce with VECTORIZED gather: lane loads uint4 (8 f16 ch),
// 8 lanes cover one 128B row, wave covers 8 rows per load instruction.
// 8 f32 acc per lane; 3 x shfl_xor final reduce. 1 cell/wave, 16 waves/block.
__global__ __launch_bounds__(1024)
void reduce_kernel(const _Float16* __restrict__ featbuf,
                   const int* __restrict__ sorted,
                   const unsigned int* __restrict__ starts,
                   const unsigned int* __restrict__ hist,
                   const float* __restrict__ b2,
                   float* __restrict__ out)
{
    __shared__ float R[16][66];
    const int lane  = threadIdx.x & 63;
    const int wv    = threadIdx.x >> 6;    // 0..15 = cell-within-block
    const int cbase = blockIdx.x * 16;
    const int cq    = lane & 7;            // channel octet: ch = cq*8 + j
    const int rsl   = lane >> 3;           // row slot 0..7

    const int cell = cbase + wv;
    const unsigned int s0  = starts[cell];
    const unsigned int cnt = hist[cell];

    float acc[8];
    #pragma unroll
    for (int j = 0; j < 8; ++j) acc[j] = 0.0f;

    for (unsigned int k = 0; k < cnt; k += 8) {
        const unsigned int kk = k + (unsigned int)rsl;
        const bool ok = kk < cnt;
        const int r = sorted[ok ? (s0 + kk) : s0];
        union { uint4 u; f16x2 h[4]; } V;
        V.u = *(const uint4*)(featbuf + (size_t)r * COUT + cq * 8);
        #pragma unroll
        for (int j = 0; j < 4; ++j) {
            acc[2 * j]     += ok ? (float)V.h[j].x : 0.0f;
            acc[2 * j + 1] += ok ? (float)V.h[j].y : 0.0f;
        }
    }
    #pragma unroll
    for (int m = 8; m <= 32; m <<= 1)
        #pragma unroll
        for (int j = 0; j < 8; ++j)
            acc[j] += __shfl_xor(acc[j], m);

    if (rsl == 0) {
        const float inv = 1.0f / fmaxf((float)cnt, 1.0f);
        float4 b2a = *(const float4*)(b2 + cq * 8);
        float4 b2b = *(const float4*)(b2 + cq * 8 + 4);
        const float bb[8] = {b2a.x, b2a.y, b2a.z, b2a.w, b2b.x, b2b.y, b2b.z, b2b.w};
        #pragma unroll
        for (int j = 0; j < 8; ++j)
            R[wv][cq * 8 + j] = cnt ? (acc[j] * inv + bb[j]) : 0.0f;
    }
    __syncthreads();

    // store: thread t -> out[ch = t>>4][cbase + (t&15)]; 64B contiguous per ch
    const int ch = threadIdx.x >> 4;
    const int ci = threadIdx.x & 15;
    out[ch * NCELL + cbase + ci] = R[ci][ch];
}

// K5 (fallback only): divide by counts + add b2 (guarded for empty cells)
__global__ void finalize_kernel(float* __restrict__ out,
                                const unsigned int* __restrict__ hist,
                                const float* __restrict__ b2)
{
    int t = blockIdx.x * 256 + threadIdx.x;
    int cell = t & (NCELL - 1);
    int ch   = t >> 16;
    float c  = (float)hist[cell];
    out[t] = out[t] / fmaxf(c, 1.0f) + ((c > 0.0f) ? b2[ch] : 0.0f);
}

extern "C" void kernel_launch(void* const* d_in, const int* in_sizes, int n_in,
                              void* d_out, int out_size, void* d_ws, size_t ws_size,
                              hipStream_t stream) {
    (void)in_sizes; (void)n_in; (void)out_size;
    const float* pos   = (const float*)d_in[0];
    const float* feats = (const float*)d_in[1];
    const float* W1    = (const float*)d_in[2];
    const float* b1    = (const float*)d_in[3];
    const float* ln_g  = (const float*)d_in[4];
    const float* ln_b  = (const float*)d_in[5];
    const float* W2    = (const float*)d_in[6];
    const float* b2    = (const float*)d_in[7];
    const int*   ax1   = (const int*)d_in[8];
    const int*   ax2   = (const int*)d_in[9];

    char* ws = (char*)d_ws;
    unsigned int* hist   = (unsigned int*)(ws + WS_HIST);
    unsigned int* starts = (unsigned int*)(ws + WS_STARTS);
    unsigned int* cr32   = (unsigned int*)(ws + WS_CR);
    int*          sorted = (int*)(ws + WS_SORT);
    _Float16*     wpk    = (_Float16*)(ws + WS_WPK);
    _Float16*     featbf = (_Float16*)(ws + WS_FEAT);

    float* out = (float*)d_out;
    const int use_feat = (ws_size >= WS_NEED) ? 1 : 0;

    hipMemsetAsync(hist, 0, NCELL * sizeof(unsigned int), stream);
    if (!use_feat)
        hipMemsetAsync(d_out, 0, (size_t)COUT * NCELL * sizeof(float), stream);

    pack_w_kernel<<<(W_HALFS + 255) / 256, 256, 0, stream>>>(W1, W2, wpk);
    mlp_mfma_kernel<<<MB_BLOCKS, 512, 0, stream>>>(
        pos, feats, wpk, b1, ln_g, ln_b, ax1, ax2, hist,
        use_feat ? cr32 : (unsigned int*)nullptr, featbf, out, use_feat);
    if (use_feat) {
        scan_fused_kernel<<<1, 1024, 0, stream>>>(hist, starts);
        build_sorted_kernel<<<PT_BLOCKS, 256, 0, stream>>>(cr32, starts, sorted);
        reduce_kernel<<<NCELL / 16, 1024, 0, stream>>>(featbf, sorted, starts, hist, b2, out);
    } else {
        finalize_kernel<<<(COUT * NCELL) / 256, 256, 0, stream>>>(out, hist, b2);
    }
}